// Round 1
// baseline (13202.150 us; speedup 1.0000x reference)
//
#include <hip/hip_runtime.h>

constexpr int B = 4, C = 512, T = 1024, H = 8, KC = 64, F = 2048, L = 6;
constexpr float EPS = 1e-4f;
constexpr float SCALE = 0.125f; // 1/sqrt(64)

// ---------------- RoPE cos/sin table: [T][16] each ----------------
__global__ __launch_bounds__(256) void rope_tab_kernel(float* __restrict__ cosT,
                                                       float* __restrict__ sinT) {
  int idx = blockIdx.x * 256 + threadIdx.x;
  if (idx >= T * 16) return;
  int t = idx >> 4, j = idx & 15;
  float theta = powf(10000.f, -(float)j / 16.f);
  float ang = (float)t * theta;
  float s, c;
  sincosf(ang, &s, &c);
  cosT[t * 16 + j] = c;
  sinT[t * 16 + j] = s;
}

// ---------------- RoPE applied in-place to q and k ----------------
__global__ __launch_bounds__(256) void rope_kernel(float* __restrict__ q, float* __restrict__ k,
                                                   const float* __restrict__ cosT,
                                                   const float* __restrict__ sinT) {
  int idx = blockIdx.x * 256 + threadIdx.x;
  if (idx >= B * H * 16 * T) return;
  int t = idx & (T - 1);
  int r = idx >> 10;
  int j = r & 15;
  int bh = r >> 4;
  size_t base = (size_t)bh * KC * T;
  size_t i1 = base + (size_t)j * T + t;
  size_t i2 = base + (size_t)(j + 16) * T + t;
  float cv = cosT[t * 16 + j], sv = sinT[t * 16 + j];
  float a = q[i1], b2 = q[i2];
  q[i1] = a * cv - b2 * sv;
  q[i2] = b2 * cv + a * sv;
  a = k[i1]; b2 = k[i2];
  k[i1] = a * cv - b2 * sv;
  k[i2] = b2 * cv + a * sv;
}

// ---------------- generic conv (KW=1 -> 1x1 GEMM, KW=3 -> conv1d pad=1) ----------------
// out[b,o,t] = act( sum_{c,k} W[o,c,k] * in[b,c,t+k-PAD] (*mask[b,t']) + bias[o] )
template<int KW, bool RELU>
__global__ __launch_bounds__(256) void conv_kernel(
    const float* __restrict__ in, const float* __restrict__ Wg,
    const float* __restrict__ bias, const float* __restrict__ mask,
    float* __restrict__ out, int Cin, int Cout)
{
  constexpr int PAD = KW / 2;
  const int b = blockIdx.z;
  const int o0 = blockIdx.y * 64;
  const int t0 = blockIdx.x * 64;
  const int tid = threadIdx.x;
  const int tt = (tid & 15) * 4;
  const int oo = (tid >> 4) * 4;

  __shared__ float sIn[16][68];
  __shared__ float sW[16 * KW][68];

  float acc[4][4] = {};
  const float* inb = in + (size_t)b * Cin * T;
  const float* mrow = mask ? mask + (size_t)b * T : nullptr;

  for (int c0 = 0; c0 < Cin; c0 += 16) {
    // stage input tile (with halo + zero pad + optional mask)
    for (int i = tid; i < 16 * (64 + 2 * PAD); i += 256) {
      int ccl = i / (64 + 2 * PAD);
      int x   = i % (64 + 2 * PAD);
      int t = t0 + x - PAD;
      float v = 0.f;
      if (t >= 0 && t < T) {
        v = inb[(size_t)(c0 + ccl) * T + t];
        if (mrow) v *= mrow[t];
      }
      sIn[ccl][x] = v;
    }
    // stage weight tile: sW[cc*KW+k][o]
    for (int i = tid; i < 64 * 16 * KW; i += 256) {
      int o = i / (16 * KW);
      int r = i % (16 * KW);
      sW[r][o] = Wg[((size_t)(o0 + o) * Cin + (c0 + r / KW)) * KW + (r % KW)];
    }
    __syncthreads();
    #pragma unroll
    for (int ccl = 0; ccl < 16; ++ccl) {
      float fin[4 + 2 * PAD];
      float4 f0 = *(const float4*)&sIn[ccl][tt];
      fin[0] = f0.x; fin[1] = f0.y; fin[2] = f0.z; fin[3] = f0.w;
      if constexpr (PAD > 0) {
        fin[4] = sIn[ccl][tt + 4];
        fin[5] = sIn[ccl][tt + 5];
      }
      #pragma unroll
      for (int k = 0; k < KW; ++k) {
        float4 wv = *(const float4*)&sW[ccl * KW + k][oo];
        float wa[4] = {wv.x, wv.y, wv.z, wv.w};
        #pragma unroll
        for (int i2 = 0; i2 < 4; ++i2)
          #pragma unroll
          for (int j = 0; j < 4; ++j)
            acc[i2][j] += wa[i2] * fin[j + k];
      }
    }
    __syncthreads();
  }
  for (int i2 = 0; i2 < 4; ++i2) {
    float bv = bias[o0 + oo + i2];
    #pragma unroll
    for (int j = 0; j < 4; ++j) {
      float v = acc[i2][j] + bv;
      if (RELU) v = fmaxf(v, 0.f);
      out[((size_t)b * Cout + o0 + oo + i2) * T + t0 + tt + j] = v;
    }
  }
}

// ---------------- scores[bz][t][s] = scale * q.k (masked) ----------------
__global__ __launch_bounds__(256) void scores_kernel(
    const float* __restrict__ q, const float* __restrict__ k,
    const float* __restrict__ mask, float* __restrict__ scores, int b0)
{
  int bz = blockIdx.z;          // bl*H + h
  int bl = bz >> 3, h = bz & 7;
  int b = b0 + bl;
  int t0 = blockIdx.y * 64, s0 = blockIdx.x * 64;
  int tid = threadIdx.x;
  int tq = (tid & 15) * 4, ts = (tid >> 4) * 4;
  __shared__ float sQ[64][68], sK[64][68];
  size_t qbase = (size_t)(b * H + h) * KC * T;
  for (int i = tid; i < 64 * 64; i += 256) {
    int cc = i >> 6, x = i & 63;
    sQ[cc][x] = q[qbase + (size_t)cc * T + t0 + x];
    sK[cc][x] = k[qbase + (size_t)cc * T + s0 + x];
  }
  __syncthreads();
  float acc[4][4] = {};
  #pragma unroll 8
  for (int cc = 0; cc < 64; ++cc) {
    float4 qf = *(const float4*)&sQ[cc][tq];
    float4 kf = *(const float4*)&sK[cc][ts];
    float qa[4] = {qf.x, qf.y, qf.z, qf.w};
    float ka[4] = {kf.x, kf.y, kf.z, kf.w};
    #pragma unroll
    for (int i2 = 0; i2 < 4; ++i2)
      #pragma unroll
      for (int j = 0; j < 4; ++j)
        acc[i2][j] += qa[i2] * ka[j];
  }
  const float* mrow = mask + (size_t)b * T;
  float* srow = scores + (size_t)bz * T * T;
  for (int i2 = 0; i2 < 4; ++i2) {
    float mq = mrow[t0 + tq + i2];
    for (int j = 0; j < 4; ++j) {
      float v = acc[i2][j] * SCALE;
      float ms = mrow[s0 + ts + j];
      if (!(mq * ms > 0.f)) v = -10000.f;
      srow[(size_t)(t0 + tq + i2) * T + (s0 + ts + j)] = v;
    }
  }
}

// ---------------- row softmax over last dim (T=1024) ----------------
__global__ __launch_bounds__(256) void softmax_kernel(float* __restrict__ scores) {
  size_t row = blockIdx.x;
  float* p = scores + row * T;
  int tid = threadIdx.x;
  float4 v = ((float4*)p)[tid];
  float m = fmaxf(fmaxf(v.x, v.y), fmaxf(v.z, v.w));
  __shared__ float red[256];
  red[tid] = m; __syncthreads();
  for (int s = 128; s > 0; s >>= 1) {
    if (tid < s) red[tid] = fmaxf(red[tid], red[tid + s]);
    __syncthreads();
  }
  m = red[0]; __syncthreads();
  v.x = __expf(v.x - m); v.y = __expf(v.y - m);
  v.z = __expf(v.z - m); v.w = __expf(v.w - m);
  float s4 = v.x + v.y + v.z + v.w;
  red[tid] = s4; __syncthreads();
  for (int s = 128; s > 0; s >>= 1) {
    if (tid < s) red[tid] += red[tid + s];
    __syncthreads();
  }
  float inv = 1.f / red[0];
  v.x *= inv; v.y *= inv; v.z *= inv; v.w *= inv;
  ((float4*)p)[tid] = v;
}

// ---------------- o[b, h*64+cc, t] = sum_s p[t,s] * v[cc,s] ----------------
__global__ __launch_bounds__(256) void pv_kernel(
    const float* __restrict__ scores, const float* __restrict__ vbuf,
    float* __restrict__ obuf, int b0)
{
  int bz = blockIdx.y;
  int bl = bz >> 3, h = bz & 7;
  int b = b0 + bl;
  int t0 = blockIdx.x * 64;
  int tid = threadIdx.x;
  int tt = (tid & 15) * 4, cc = (tid >> 4) * 4;
  __shared__ float sP[32][68], sV[32][68];
  size_t vbase = (size_t)(b * H + h) * KC * T;
  const float* sc = scores + (size_t)bz * T * T;
  float acc[4][4] = {};
  for (int s0 = 0; s0 < T; s0 += 32) {
    for (int i = tid; i < 64 * 32; i += 256) {
      int r = i >> 5, ss = i & 31;
      sP[ss][r] = sc[(size_t)(t0 + r) * T + s0 + ss];
      sV[ss][r] = vbuf[vbase + (size_t)r * T + s0 + ss];
    }
    __syncthreads();
    #pragma unroll 8
    for (int ss = 0; ss < 32; ++ss) {
      float4 pf = *(const float4*)&sP[ss][tt];
      float4 vf = *(const float4*)&sV[ss][cc];
      float pa[4] = {pf.x, pf.y, pf.z, pf.w};
      float va[4] = {vf.x, vf.y, vf.z, vf.w};
      #pragma unroll
      for (int i2 = 0; i2 < 4; ++i2)
        #pragma unroll
        for (int j = 0; j < 4; ++j)
          acc[i2][j] += va[i2] * pa[j];
    }
    __syncthreads();
  }
  for (int i2 = 0; i2 < 4; ++i2)
    for (int j = 0; j < 4; ++j)
      obuf[vbase + (size_t)(cc + i2) * T + t0 + tt + j] = acc[i2][j];
}

// ---------------- fused residual + layernorm over channel dim ----------------
// out[b,c,t] = LN_c( a*maskA? + y*maskY? ) * gamma + beta
__global__ __launch_bounds__(256) void ln_kernel(
    const float* __restrict__ a, const float* __restrict__ y,
    const float* __restrict__ gamma, const float* __restrict__ beta,
    const float* __restrict__ mask, int maskA, int maskY,
    float* __restrict__ outp)
{
  int b = blockIdx.y;
  int t0 = blockIdx.x * 32;
  int tid = threadIdx.x;
  int tl = tid & 31, g = tid >> 5;
  __shared__ float sVal[C][33];
  __shared__ float sS[8][32], sQ2[8][32];
  __shared__ float sMean[32], sRstd[32];
  float m = mask[(size_t)b * T + t0 + tl];
  float sum = 0.f, sq = 0.f;
  size_t base = ((size_t)b * C) * T + t0 + tl;
  for (int c = g * 64; c < g * 64 + 64; ++c) {
    float av = a[base + (size_t)c * T];
    if (maskA) av *= m;
    float yv = y[base + (size_t)c * T];
    if (maskY) yv *= m;
    av += yv;
    sVal[c][tl] = av;
    sum += av; sq += av * av;
  }
  sS[g][tl] = sum; sQ2[g][tl] = sq;
  __syncthreads();
  if (tid < 32) {
    float s = 0.f, q2 = 0.f;
    for (int gg = 0; gg < 8; ++gg) { s += sS[gg][tid]; q2 += sQ2[gg][tid]; }
    float mean = s * (1.f / C);
    float var = q2 * (1.f / C) - mean * mean;
    sMean[tid] = mean;
    sRstd[tid] = rsqrtf(var + EPS);
  }
  __syncthreads();
  float mean = sMean[tl], rstd = sRstd[tl];
  for (int c = g * 64; c < g * 64 + 64; ++c) {
    float v = (sVal[c][tl] - mean) * rstd * gamma[c] + beta[c];
    outp[base + (size_t)c * T] = v;
  }
}

__global__ __launch_bounds__(256) void finalize_kernel(const float* __restrict__ xb,
                                                       const float* __restrict__ mask,
                                                       float* __restrict__ out) {
  size_t idx = (size_t)blockIdx.x * 256 + threadIdx.x;
  if (idx >= (size_t)B * C * T) return;
  int t = (int)(idx & (T - 1));
  int b = (int)(idx / ((size_t)C * T));
  out[idx] = xb[idx] * mask[(size_t)b * T + t];
}

extern "C" void kernel_launch(void* const* d_in, const int* in_sizes, int n_in,
                              void* d_out, int out_size, void* d_ws, size_t ws_size,
                              hipStream_t stream)
{
  const float* x   = (const float*)d_in[0];
  const float* msk = (const float*)d_in[1];
  const float* Wq  = (const float*)d_in[2];
  const float* bq  = (const float*)d_in[3];
  const float* Wk  = (const float*)d_in[4];
  const float* bk  = (const float*)d_in[5];
  const float* Wv  = (const float*)d_in[6];
  const float* bv  = (const float*)d_in[7];
  const float* Wo  = (const float*)d_in[8];
  const float* bo  = (const float*)d_in[9];
  const float* g1  = (const float*)d_in[10];
  const float* be1 = (const float*)d_in[11];
  const float* W1  = (const float*)d_in[12];
  const float* c1  = (const float*)d_in[13];
  const float* W2  = (const float*)d_in[14];
  const float* c2  = (const float*)d_in[15];
  const float* g2  = (const float*)d_in[16];
  const float* be2 = (const float*)d_in[17];

  const size_t NBCT = (size_t)B * C * T;
  float* ws = (float*)d_ws;
  float* xb    = ws;
  float* qb    = xb + NBCT;
  float* kb    = qb + NBCT;
  float* vb    = kb + NBCT;
  float* ob    = vb + NBCT;
  float* tmp   = ob + NBCT;
  float* ropeC = tmp + NBCT;
  float* ropeS = ropeC + (size_t)T * 16;
  float* un    = ropeS + (size_t)T * 16;   // union: scores | hb
  float* hb     = un;
  float* scores = un;

  size_t availF   = ws_size / sizeof(float);
  size_t needFull = (size_t)(un - ws) + (size_t)B * H * T * T;
  bool fullB = (availF >= needFull);

  hipMemcpyAsync(xb, x, NBCT * sizeof(float), hipMemcpyDeviceToDevice, stream);
  rope_tab_kernel<<<(T * 16 + 255) / 256, 256, 0, stream>>>(ropeC, ropeS);

  for (int i = 0; i < L; ++i) {
    const float* Wq_i = Wq + (size_t)i * C * C;
    const float* Wk_i = Wk + (size_t)i * C * C;
    const float* Wv_i = Wv + (size_t)i * C * C;
    const float* Wo_i = Wo + (size_t)i * C * C;
    const float* bq_i = bq + (size_t)i * C;
    const float* bk_i = bk + (size_t)i * C;
    const float* bv_i = bv + (size_t)i * C;
    const float* bo_i = bo + (size_t)i * C;
    const float* W1_i = W1 + (size_t)i * F * C * 3;
    const float* c1_i = c1 + (size_t)i * F;
    const float* W2_i = W2 + (size_t)i * C * F * 3;
    const float* c2_i = c2 + (size_t)i * C;

    dim3 gProj(T / 64, C / 64, B);
    conv_kernel<1, false><<<gProj, 256, 0, stream>>>(xb, Wq_i, bq_i, msk, qb, C, C);
    conv_kernel<1, false><<<gProj, 256, 0, stream>>>(xb, Wk_i, bk_i, msk, kb, C, C);
    conv_kernel<1, false><<<gProj, 256, 0, stream>>>(xb, Wv_i, bv_i, msk, vb, C, C);
    rope_kernel<<<(B * H * 16 * T + 255) / 256, 256, 0, stream>>>(qb, kb, ropeC, ropeS);

    if (fullB) {
      scores_kernel<<<dim3(T / 64, T / 64, B * H), 256, 0, stream>>>(qb, kb, msk, scores, 0);
      softmax_kernel<<<B * H * T, 256, 0, stream>>>(scores);
      pv_kernel<<<dim3(T / 64, B * H), 256, 0, stream>>>(scores, vb, ob, 0);
    } else {
      for (int b0 = 0; b0 < B; ++b0) {
        scores_kernel<<<dim3(T / 64, T / 64, H), 256, 0, stream>>>(qb, kb, msk, scores, b0);
        softmax_kernel<<<H * T, 256, 0, stream>>>(scores);
        pv_kernel<<<dim3(T / 64, H), 256, 0, stream>>>(scores, vb, ob, b0);
      }
    }

    conv_kernel<1, false><<<gProj, 256, 0, stream>>>(ob, Wo_i, bo_i, nullptr, tmp, C, C);
    ln_kernel<<<dim3(T / 32, B), 256, 0, stream>>>(xb, tmp, g1 + (size_t)i * C, be1 + (size_t)i * C,
                                                   msk, 1, 0, xb);
    conv_kernel<3, true><<<dim3(T / 64, F / 64, B), 256, 0, stream>>>(xb, W1_i, c1_i, msk, hb, C, F);
    conv_kernel<3, false><<<dim3(T / 64, C / 64, B), 256, 0, stream>>>(hb, W2_i, c2_i, msk, tmp, F, C);
    ln_kernel<<<dim3(T / 32, B), 256, 0, stream>>>(xb, tmp, g2 + (size_t)i * C, be2 + (size_t)i * C,
                                                   msk, 0, 1, xb);
  }
  finalize_kernel<<<(int)((NBCT + 255) / 256), 256, 0, stream>>>(xb, msk, (float*)d_out);
}

// Round 2
// 1460.958 us; speedup vs baseline: 9.0366x; 9.0366x over previous
//
#include <hip/hip_runtime.h>

typedef __bf16 bf16;
typedef _Float16 f16;
typedef __bf16 bf16x8 __attribute__((ext_vector_type(8)));
typedef __bf16 bf16x4v __attribute__((ext_vector_type(4)));
typedef _Float16 f16x4v __attribute__((ext_vector_type(4)));
typedef float f32x4 __attribute__((ext_vector_type(4)));

constexpr int B = 4, C = 512, T = 1024, H = 8, F = 2048, L = 6;
constexpr int TP = T + 18;               // padded rows: row0 = zero, rows T+1..T+17 zero
constexpr float SCALE = 0.125f, EPS = 1e-4f;

// ---------------------------------------------------------------------------
// global -> LDS staging: nChunks x 1KB, rows of 64B from global with rowStrideB.
// LDS stays linear; bank-swizzle is applied by permuting the per-lane GLOBAL
// source (involution), matched by the same XOR on the ds_read side.
// ---------------------------------------------------------------------------
__device__ __forceinline__ void stage_rows(const char* g, long strideB, char* lds,
                                           int nChunks, int tid) {
  const int wave = tid >> 6, lane = tid & 63;
  for (int c = wave; c < nChunks; c += 4) {
    int row = (c << 4) + (lane >> 2);
    int kq = (lane & 3) ^ ((row >> 1) & 3);           // inverse-swizzle source
    const char* src = g + (long)row * strideB + kq * 16;
    char* dst = lds + ((long)c << 10);                // wave-uniform base
    __builtin_amdgcn_global_load_lds((const __attribute__((address_space(1))) void*)src,
                                     (__attribute__((address_space(3))) void*)dst,
                                     16, 0, 0);
  }
}

// ---------------------------------------------------------------------------
// NT GEMM: D[m][n] = sum_k A[m][k] * Bw[n][k]  (+ shifted variants for KW=3)
// A rows are t (with +-1 halo for KW=3 via padded buffers), Bw rows are n.
// EPI: 0 = bf16 [m][ldo] (+bias, relu, maskM opts)
//      1 = f16  [m][ldo] * SCALE (scores)
//      2 = QKV split: n<512 -> O(q), <1024 -> O2(k), else O3 = vT[n-1024][m]
// ---------------------------------------------------------------------------
template <int BM, int BN, int KW, int EPI, bool RELU, bool MASKM, int ZD, bool AZL, bool OZL>
__global__ __launch_bounds__(256, 2) void gemm_kernel(
    const bf16* __restrict__ A, const bf16* __restrict__ Bw,
    const float* __restrict__ bias, const float* __restrict__ mask,
    bf16* __restrict__ O, bf16* __restrict__ O2, bf16* __restrict__ O3,
    int lda, int ldb, int ldo, int K, long bSlice,
    long aZ1, long aZ2, long bZ1, long bZ2, long oZ1, long oZ2, int zoff)
{
  constexpr int WTM = BM / 2, WTN = BN / 2, FM = WTM / 16, FN = WTN / 16;
  constexpr int RA = (KW == 3) ? BM + 16 : BM;
  constexpr int ACH = RA / 16;       // 1KB chunks for A
  constexpr int BCH = BN / 16;       // per B slice
  __shared__ __align__(128) bf16 sA[RA * 32];
  __shared__ __align__(128) bf16 sB[KW * BN * 32];

  const int tid = threadIdx.x;
  const int zl = blockIdx.z, zg = zl + zoff;
  const int zb = zg / ZD, zh = zg % ZD;
  const long aOff = AZL ? (long)zl * aZ1 : (long)zb * aZ1 + (long)zh * aZ2;
  const long bOff = (long)zb * bZ1 + (long)zh * bZ2;
  const long oOff = OZL ? (long)zl * oZ1 : (long)zb * oZ1 + (long)zh * oZ2;
  const int m0 = blockIdx.x * BM, n0 = blockIdx.y * BN;
  const bf16* Ab = A + aOff + (long)m0 * lda;
  const bf16* Bb = Bw + bOff + (long)n0 * ldb;

  const int wid = tid >> 6, lane = tid & 63;
  const int wm = wid >> 1, wn = wid & 1;
  const int l16 = lane & 15, q4 = lane >> 4;

  f32x4 acc[FM][FN] = {};

  for (int k0 = 0; k0 < K; k0 += 32) {
    stage_rows((const char*)(Ab + k0), (long)lda * 2, (char*)sA, ACH, tid);
    #pragma unroll
    for (int kw = 0; kw < KW; ++kw)
      stage_rows((const char*)(Bb + (long)kw * bSlice + k0), (long)ldb * 2,
                 (char*)sB + kw * BN * 64, BCH, tid);
    __syncthreads();
    #pragma unroll
    for (int kw = 0; kw < KW; ++kw) {
      bf16x8 af[FM], bfr[FN];
      #pragma unroll
      for (int fm = 0; fm < FM; ++fm) {
        int row = wm * WTM + fm * 16 + l16 + (KW == 3 ? kw : 0);
        unsigned ad = (unsigned)(row * 64 + q4 * 16);
        ad ^= ((ad >> 7) & 3u) << 4;
        af[fm] = *(const bf16x8*)((const char*)sA + ad);
      }
      #pragma unroll
      for (int fn = 0; fn < FN; ++fn) {
        int rn = wn * WTN + fn * 16 + l16;
        unsigned bd = (unsigned)(rn * 64 + q4 * 16);
        bd ^= ((bd >> 7) & 3u) << 4;
        bfr[fn] = *(const bf16x8*)((const char*)sB + kw * BN * 64 + bd);
      }
      #pragma unroll
      for (int fm = 0; fm < FM; ++fm)
        #pragma unroll
        for (int fn = 0; fn < FN; ++fn)
          acc[fm][fn] = __builtin_amdgcn_mfma_f32_16x16x32_bf16(af[fm], bfr[fn],
                                                                acc[fm][fn], 0, 0, 0);
    }
    __syncthreads();
  }

  // epilogue: C/D layout col=lane&15, row=(lane>>4)*4+i  [m89-verified]
  #pragma unroll
  for (int fn = 0; fn < FN; ++fn) {
    const int nl = n0 + wn * WTN + fn * 16 + l16;
    const float bv = (EPI == 1 || bias == nullptr) ? 0.f : bias[nl];
    #pragma unroll
    for (int fm = 0; fm < FM; ++fm) {
      const int mb = m0 + wm * WTM + fm * 16 + q4 * 4;
      f32x4 v = acc[fm][fn];
      float vals[4];
      #pragma unroll
      for (int i = 0; i < 4; ++i) {
        float t = v[i] + bv;
        if (RELU) t = fmaxf(t, 0.f);
        if (MASKM) t *= mask[(long)zb * T + mb + i];
        vals[i] = t;
      }
      if constexpr (EPI == 1) {
        f16* dst = (f16*)O + oOff;
        #pragma unroll
        for (int i = 0; i < 4; ++i)
          dst[(long)(mb + i) * ldo + nl] = (f16)(vals[i] * SCALE);
      } else if constexpr (EPI == 2) {
        if (nl < 1024) {
          bf16* dst = (nl < 512 ? O : O2) + oOff + (nl & 511);
          #pragma unroll
          for (int i = 0; i < 4; ++i)
            dst[(long)(mb + i) * C] = (bf16)vals[i];
        } else {
          bf16x4v tv;
          #pragma unroll
          for (int i = 0; i < 4; ++i) tv[i] = (bf16)vals[i];
          *(bf16x4v*)(O3 + oOff + (long)(nl - 1024) * T + mb) = tv;
        }
      } else {
        bf16* dst = O + oOff;
        #pragma unroll
        for (int i = 0; i < 4; ++i)
          dst[(long)(mb + i) * ldo + nl] = (bf16)vals[i];
      }
    }
  }
}

// ---------------- RoPE table ----------------
__global__ __launch_bounds__(256) void rope_tab_kernel(float* __restrict__ cosT,
                                                       float* __restrict__ sinT) {
  int idx = blockIdx.x * 256 + threadIdx.x;
  if (idx >= T * 16) return;
  int t = idx >> 4, j = idx & 15;
  float theta = powf(10000.f, -(float)j / 16.f);
  float s, c;
  sincosf((float)t * theta, &s, &c);
  cosT[idx] = c;
  sinT[idx] = s;
}

// ---------------- RoPE on bf16 q,k in [b][t][C] layout ----------------
__global__ __launch_bounds__(256) void rope_kernel(bf16* __restrict__ q, bf16* __restrict__ k,
                                                   const float* __restrict__ cosT,
                                                   const float* __restrict__ sinT) {
  int idx = blockIdx.x * 256 + threadIdx.x;   // B*T*H*16 = 2^19
  int j = idx & 15, h = (idx >> 4) & 7, t = (idx >> 7) & 1023, b = idx >> 17;
  long base = ((long)b * T + t) * C + h * 64 + j;
  float cv = cosT[t * 16 + j], sv = sinT[t * 16 + j];
  float a = (float)q[base], b2 = (float)q[base + 16];
  q[base] = (bf16)(a * cv - b2 * sv);
  q[base + 16] = (bf16)(b2 * cv + a * sv);
  a = (float)k[base]; b2 = (float)k[base + 16];
  k[base] = (bf16)(a * cv - b2 * sv);
  k[base + 16] = (bf16)(b2 * cv + a * sv);
}

// ---------------- in-place softmax: f16 scores -> bf16 probs ----------------
__global__ __launch_bounds__(256) void softmax_kernel(bf16* __restrict__ sp,
                                                      const float* __restrict__ mask, int zoff) {
  const long row = blockIdx.x;                 // zl*T + t
  const int zl = (int)(row >> 10), t = (int)(row & 1023);
  const int b = (zl + zoff) >> 3;
  const int tid = threadIdx.x;
  const f16* src = (const f16*)sp + row * T;
  f16x4v v = *(const f16x4v*)(src + tid * 4);
  const float mt = mask[(long)b * T + t];
  float sc[4];
  #pragma unroll
  for (int i = 0; i < 4; ++i) {
    float ms = mask[(long)b * T + tid * 4 + i];
    sc[i] = (mt * ms > 0.f) ? (float)v[i] : -10000.f;
  }
  __shared__ float red[256];
  float mx = fmaxf(fmaxf(sc[0], sc[1]), fmaxf(sc[2], sc[3]));
  red[tid] = mx; __syncthreads();
  for (int s = 128; s > 0; s >>= 1) {
    if (tid < s) red[tid] = fmaxf(red[tid], red[tid + s]);
    __syncthreads();
  }
  mx = red[0]; __syncthreads();
  float e[4], ssum = 0.f;
  #pragma unroll
  for (int i = 0; i < 4; ++i) { e[i] = __expf(sc[i] - mx); ssum += e[i]; }
  red[tid] = ssum; __syncthreads();
  for (int s = 128; s > 0; s >>= 1) {
    if (tid < s) red[tid] += red[tid + s];
    __syncthreads();
  }
  float inv = 1.f / red[0];
  bf16x4v p;
  #pragma unroll
  for (int i = 0; i < 4; ++i) p[i] = (bf16)(e[i] * inv);
  *(bf16x4v*)((bf16*)sp + row * T + tid * 4) = p;
}

// ---------------- fused residual + LayerNorm over contiguous C ----------------
__global__ __launch_bounds__(256) void ln_kernel(
    const float* __restrict__ x, const bf16* __restrict__ y,
    const float* __restrict__ gamma, const float* __restrict__ beta,
    const float* __restrict__ mask, int maskA, int maskY,
    float* __restrict__ xout, bf16* __restrict__ xm)
{
  const int w = threadIdx.x >> 6, lane = threadIdx.x & 63;
  const long row = (long)blockIdx.x * 4 + w;     // b*T + t
  const int b = (int)(row >> 10), t = (int)(row & 1023);
  const float* xr = x + row * C;
  const bf16* yr = y + row * C;
  const float m = mask[(long)b * T + t];
  const float fa = maskA ? m : 1.f, fy = maskY ? m : 1.f;
  float4 x0 = *(const float4*)(xr + lane * 8);
  float4 x1 = *(const float4*)(xr + lane * 8 + 4);
  bf16x8 yv = *(const bf16x8*)(yr + lane * 8);
  float vals[8] = {x0.x, x0.y, x0.z, x0.w, x1.x, x1.y, x1.z, x1.w};
  float sum = 0.f, sq = 0.f;
  #pragma unroll
  for (int i = 0; i < 8; ++i) {
    vals[i] = vals[i] * fa + (float)yv[i] * fy;
    sum += vals[i]; sq += vals[i] * vals[i];
  }
  #pragma unroll
  for (int s = 1; s < 64; s <<= 1) {
    sum += __shfl_xor(sum, s, 64);
    sq  += __shfl_xor(sq, s, 64);
  }
  float mean = sum * (1.f / C);
  float rstd = rsqrtf(sq * (1.f / C) - mean * mean + EPS);
  float4 g0 = *(const float4*)(gamma + lane * 8), g1v = *(const float4*)(gamma + lane * 8 + 4);
  float4 b0 = *(const float4*)(beta + lane * 8),  b1v = *(const float4*)(beta + lane * 8 + 4);
  float gg[8] = {g0.x, g0.y, g0.z, g0.w, g1v.x, g1v.y, g1v.z, g1v.w};
  float bb[8] = {b0.x, b0.y, b0.z, b0.w, b1v.x, b1v.y, b1v.z, b1v.w};
  float o[8]; bf16x8 xmv;
  #pragma unroll
  for (int i = 0; i < 8; ++i) {
    o[i] = (vals[i] - mean) * rstd * gg[i] + bb[i];
    xmv[i] = (bf16)(o[i] * m);
  }
  *(float4*)(xout + row * C + lane * 8)     = make_float4(o[0], o[1], o[2], o[3]);
  *(float4*)(xout + row * C + lane * 8 + 4) = make_float4(o[4], o[5], o[6], o[7]);
  *(bf16x8*)(xm + ((long)b * TP + t + 1) * C + lane * 8) = xmv;
}

// ---------------- transposes [b][C][T] <-> [b][t][C] ----------------
__global__ __launch_bounds__(256) void transpose_in_kernel(const float* __restrict__ xin,
                                                           const float* __restrict__ mask,
                                                           float* __restrict__ x,
                                                           bf16* __restrict__ xm) {
  __shared__ float tile[32][33];
  int tx = threadIdx.x, ty = threadIdx.y;
  int t0 = blockIdx.x * 32, c0 = blockIdx.y * 32, b = blockIdx.z;
  #pragma unroll
  for (int i = 0; i < 4; ++i)
    tile[ty + i * 8][tx] = xin[((long)b * C + c0 + ty + i * 8) * T + t0 + tx];
  __syncthreads();
  #pragma unroll
  for (int i = 0; i < 4; ++i) {
    int t = t0 + ty + i * 8;
    float val = tile[tx][ty + i * 8];
    float m = mask[(long)b * T + t];
    x[((long)b * T + t) * C + c0 + tx] = val;
    xm[((long)b * TP + t + 1) * C + c0 + tx] = (bf16)(val * m);
  }
}

__global__ __launch_bounds__(256) void transpose_out_kernel(const float* __restrict__ x,
                                                            const float* __restrict__ mask,
                                                            float* __restrict__ out) {
  __shared__ float tile[32][33];
  int tx = threadIdx.x, ty = threadIdx.y;
  int t0 = blockIdx.x * 32, c0 = blockIdx.y * 32, b = blockIdx.z;
  #pragma unroll
  for (int i = 0; i < 4; ++i)
    tile[ty + i * 8][tx] = x[((long)b * T + t0 + ty + i * 8) * C + c0 + tx];
  __syncthreads();
  #pragma unroll
  for (int i = 0; i < 4; ++i) {
    int t = t0 + tx;
    out[((long)b * C + c0 + ty + i * 8) * T + t] = tile[tx][ty + i * 8] * mask[(long)b * T + t];
  }
}

// ---------------- zero halo rows of padded activation buffers ----------------
__global__ __launch_bounds__(256) void zero_pads_kernel(bf16* __restrict__ xm, bf16* __restrict__ h) {
  long idx = (long)blockIdx.x * 256 + threadIdx.x;
  const long n1 = (long)B * 18 * C;
  const long n2 = (long)B * 18 * F;
  if (idx < n1) {
    int c = (int)(idx % C); int r = (int)((idx / C) % 18); int b = (int)(idx / (18L * C));
    int p = (r == 0) ? 0 : (T + r);
    xm[((long)b * TP + p) * C + c] = (bf16)0.f;
  } else if (idx < n1 + n2) {
    long j = idx - n1;
    int c = (int)(j % F); int r = (int)((j / F) % 18); int b = (int)(j / (18L * F));
    int p = (r == 0) ? 0 : (T + r);
    h[((long)b * TP + p) * F + c] = (bf16)0.f;
  }
}

// ---------------- weight fp32 -> bf16 with [KW][N][K] split ----------------
__global__ __launch_bounds__(256) void cvt_w_kernel(const float* __restrict__ src,
                                                    bf16* __restrict__ dst,
                                                    int N, int Kd, int KW, long total) {
  long idx = (long)blockIdx.x * 256 + threadIdx.x;
  if (idx >= total) return;
  int c = (int)(idx % Kd);
  long r = idx / Kd;
  int n = (int)(r % N);
  int k = (int)(r / N);
  dst[idx] = (bf16)src[((long)n * Kd + c) * KW + k];
}

__global__ __launch_bounds__(256) void catb_kernel(const float* __restrict__ a,
                                                   const float* __restrict__ b,
                                                   const float* __restrict__ c,
                                                   float* __restrict__ dst) {
  int i = blockIdx.x * 256 + threadIdx.x;
  if (i < 512) dst[i] = a[i];
  else if (i < 1024) dst[i] = b[i - 512];
  else if (i < 1536) dst[i] = c[i - 1024];
}

// ---------------------------------------------------------------------------
extern "C" void kernel_launch(void* const* d_in, const int* in_sizes, int n_in,
                              void* d_out, int out_size, void* d_ws, size_t ws_size,
                              hipStream_t stream)
{
  const float* xin = (const float*)d_in[0];
  const float* msk = (const float*)d_in[1];
  const float* Wq  = (const float*)d_in[2];
  const float* bq  = (const float*)d_in[3];
  const float* Wk  = (const float*)d_in[4];
  const float* bk  = (const float*)d_in[5];
  const float* Wv  = (const float*)d_in[6];
  const float* bv  = (const float*)d_in[7];
  const float* Wo  = (const float*)d_in[8];
  const float* bo  = (const float*)d_in[9];
  const float* g1  = (const float*)d_in[10];
  const float* be1 = (const float*)d_in[11];
  const float* W1  = (const float*)d_in[12];
  const float* c1  = (const float*)d_in[13];
  const float* W2  = (const float*)d_in[14];
  const float* c2  = (const float*)d_in[15];
  const float* g2  = (const float*)d_in[16];
  const float* be2 = (const float*)d_in[17];

  // ---- workspace carve (1KB aligned) ----
  size_t off = 0;
  char* base = (char*)d_ws;
  auto alloc = [&](size_t bytes) -> char* {
    char* r = base + off;
    off = (off + bytes + 1023) & ~(size_t)1023;
    return r;
  };
  float* x     = (float*)alloc((size_t)B * T * C * 4);
  float* ropeC = (float*)alloc((size_t)T * 16 * 4);
  float* ropeS = (float*)alloc((size_t)T * 16 * 4);
  float* bqkv  = (float*)alloc(1536 * 4);
  bf16* xm  = (bf16*)alloc((size_t)B * TP * C * 2);
  bf16* hb  = (bf16*)alloc((size_t)B * TP * F * 2);
  bf16* q   = (bf16*)alloc((size_t)B * T * C * 2);
  bf16* k   = (bf16*)alloc((size_t)B * T * C * 2);
  bf16* vT  = (bf16*)alloc((size_t)B * T * C * 2);
  bf16* o   = (bf16*)alloc((size_t)B * T * C * 2);
  bf16* yb  = (bf16*)alloc((size_t)B * T * C * 2);
  bf16* wqkv = (bf16*)alloc((size_t)3 * C * C * 2);
  bf16* wo   = (bf16*)alloc((size_t)C * C * 2);
  bf16* w1b  = (bf16*)alloc((size_t)3 * F * C * 2);
  bf16* w2b  = (bf16*)alloc((size_t)3 * C * F * 2);
  size_t fixedBytes = off;
  bool fullB = (ws_size >= fixedBytes + (size_t)32 * T * T * 2 + 2048);
  int zmax = fullB ? 32 : 8;
  bf16* scoresP = (bf16*)alloc((size_t)zmax * T * T * 2);
  (void)in_sizes; (void)n_in; (void)out_size;

  // ---- prologue ----
  {
    long tot = (long)B * 18 * (C + F);
    zero_pads_kernel<<<(int)((tot + 255) / 256), 256, 0, stream>>>(xm, hb);
  }
  transpose_in_kernel<<<dim3(T / 32, C / 32, B), dim3(32, 8), 0, stream>>>(xin, msk, x, xm);
  rope_tab_kernel<<<(T * 16 + 255) / 256, 256, 0, stream>>>(ropeC, ropeS);

  for (int i = 0; i < L; ++i) {
    const float* Wq_i = Wq + (size_t)i * C * C;
    const float* Wk_i = Wk + (size_t)i * C * C;
    const float* Wv_i = Wv + (size_t)i * C * C;
    const float* Wo_i = Wo + (size_t)i * C * C;
    const float* W1_i = W1 + (size_t)i * F * C * 3;
    const float* W2_i = W2 + (size_t)i * C * F * 3;

    // weight conversion (bf16, per-layer reuse)
    long tq = (long)C * C;
    cvt_w_kernel<<<(int)((tq + 255) / 256), 256, 0, stream>>>(Wq_i, wqkv, C, C, 1, tq);
    cvt_w_kernel<<<(int)((tq + 255) / 256), 256, 0, stream>>>(Wk_i, wqkv + tq, C, C, 1, tq);
    cvt_w_kernel<<<(int)((tq + 255) / 256), 256, 0, stream>>>(Wv_i, wqkv + 2 * tq, C, C, 1, tq);
    cvt_w_kernel<<<(int)((tq + 255) / 256), 256, 0, stream>>>(Wo_i, wo, C, C, 1, tq);
    long t1 = 3L * F * C;
    cvt_w_kernel<<<(int)((t1 + 255) / 256), 256, 0, stream>>>(W1_i, w1b, F, C, 3, t1);
    cvt_w_kernel<<<(int)((t1 + 255) / 256), 256, 0, stream>>>(W2_i, w2b, C, F, 3, t1);
    catb_kernel<<<6, 256, 0, stream>>>(bq + (size_t)i * C, bk + (size_t)i * C, bv + (size_t)i * C, bqkv);

    // fused QKV projection (N=1536), v stored transposed
    gemm_kernel<128, 128, 1, 2, false, false, 1, false, false>
        <<<dim3(8, 12, B), 256, 0, stream>>>(
        xm + C, wqkv, bqkv, msk, q, k, vT,
        C, C, C, C, 0,
        (long)TP * C, 0, 0, 0, (long)T * C, 0, 0);

    rope_kernel<<<(B * T * H * 16) / 256, 256, 0, stream>>>(q, k, ropeC, ropeS);

    // attention: scores (f16) -> softmax (bf16 in place) -> PV
    int nPass = fullB ? 1 : B;
    int zcnt = fullB ? 32 : 8;
    for (int p = 0; p < nPass; ++p) {
      int zoff = p * 8 * (fullB ? 0 : 1) + (fullB ? 0 : p * 0);  // per-batch: zoff = p*8
      zoff = fullB ? 0 : p * 8;
      gemm_kernel<128, 128, 1, 1, false, false, 8, false, true>
          <<<dim3(8, 8, zcnt), 256, 0, stream>>>(
          q, k, nullptr, msk, scoresP, nullptr, nullptr,
          C, C, T, 64, 0,
          (long)T * C, 64, (long)T * C, 64, (long)T * T, 0, zoff);
      softmax_kernel<<<zcnt * T, 256, 0, stream>>>(scoresP, msk, zoff);
      gemm_kernel<128, 64, 1, 0, false, false, 8, true, false>
          <<<dim3(8, 1, zcnt), 256, 0, stream>>>(
          scoresP, vT, nullptr, msk, o, nullptr, nullptr,
          T, T, C, T, 0,
          (long)T * T, 0, (long)C * T, (long)64 * T, (long)T * C, 64, zoff);
    }

    // O projection
    gemm_kernel<128, 128, 1, 0, false, false, 1, false, false>
        <<<dim3(8, 4, B), 256, 0, stream>>>(
        o, wo, bo + (size_t)i * C, msk, yb, nullptr, nullptr,
        C, C, C, C, 0,
        (long)T * C, 0, 0, 0, (long)T * C, 0, 0);

    ln_kernel<<<B * T / 4, 256, 0, stream>>>(x, yb, g1 + (size_t)i * C, be1 + (size_t)i * C,
                                             msk, 1, 0, x, xm);

    // FFN conv1 (K=3, relu, masked output)
    gemm_kernel<128, 128, 3, 0, true, true, 1, false, false>
        <<<dim3(8, 16, B), 256, 0, stream>>>(
        xm, w1b, c1 + (size_t)i * F, msk, hb + F, nullptr, nullptr,
        C, C, F, C, (long)F * C,
        (long)TP * C, 0, 0, 0, (long)TP * F, 0, 0);

    // FFN conv2 (K=3)
    gemm_kernel<128, 64, 3, 0, false, false, 1, false, false>
        <<<dim3(8, 8, B), 256, 0, stream>>>(
        hb, w2b, c2 + (size_t)i * C, msk, yb, nullptr, nullptr,
        F, F, C, F, (long)C * F,
        (long)TP * F, 0, 0, 0, (long)T * C, 0, 0);

    ln_kernel<<<B * T / 4, 256, 0, stream>>>(x, yb, g2 + (size_t)i * C, be2 + (size_t)i * C,
                                             msk, 0, 1, x, xm);
  }

  transpose_out_kernel<<<dim3(T / 32, C / 32, B), dim3(32, 8), 0, stream>>>(x, msk, (float*)d_out);
}

// Round 3
// 1321.436 us; speedup vs baseline: 9.9908x; 1.1056x over previous
//
#include <hip/hip_runtime.h>

typedef __bf16 bf16;
typedef _Float16 f16;
typedef __bf16 bf16x8 __attribute__((ext_vector_type(8)));
typedef __bf16 bf16x4v __attribute__((ext_vector_type(4)));
typedef _Float16 f16x4v __attribute__((ext_vector_type(4)));
typedef float f32x4 __attribute__((ext_vector_type(4)));

constexpr int B = 4, C = 512, T = 1024, H = 8, F = 2048, L = 6;
constexpr int TP = T + 18;               // padded rows: row0 = zero, rows T+1..T+17 zero
constexpr float SCALE = 0.125f, EPS = 1e-4f;

// ---------------------------------------------------------------------------
// global -> LDS staging: nChunks x 1KB, rows of 64B from global with rowStrideB.
// LDS stays linear; bank-swizzle is applied by permuting the per-lane GLOBAL
// source (involution), matched by the same XOR on the ds_read side.
// ---------------------------------------------------------------------------
__device__ __forceinline__ void stage_rows(const char* g, long strideB, char* lds,
                                           int nChunks, int tid) {
  const int wave = tid >> 6, lane = tid & 63;
  for (int c = wave; c < nChunks; c += 4) {
    int row = (c << 4) + (lane >> 2);
    int kq = (lane & 3) ^ ((row >> 1) & 3);           // inverse-swizzle source
    const char* src = g + (long)row * strideB + kq * 16;
    char* dst = lds + ((long)c << 10);                // wave-uniform base
    __builtin_amdgcn_global_load_lds((const __attribute__((address_space(1))) void*)src,
                                     (__attribute__((address_space(3))) void*)dst,
                                     16, 0, 0);
  }
}

// ---------------------------------------------------------------------------
// NT GEMM with 2-phase prefetch pipeline (double-buffered LDS).
// D[m][n] = sum_k A[m][k] * Bw[n][k]  (+ kw-shifted A rows for KW=3)
// EPI: 0 = bf16 [m][ldo] (+bias, relu, maskM opts)
//      1 = f16  [m][ldo] * SCALE (scores)
//      2 = QKV split: n<512 -> O(q), <1024 -> O2(k), else O3 = vT[n-1024][m]
// ---------------------------------------------------------------------------
template <int BM, int BN, int KW, int EPI, bool RELU, bool MASKM, int ZD,
          bool AZL, bool OZL, int MINW>
__global__ __launch_bounds__(256, MINW) void gemm_kernel(
    const bf16* __restrict__ A, const bf16* __restrict__ Bw,
    const float* __restrict__ bias, const float* __restrict__ mask,
    bf16* __restrict__ O, bf16* __restrict__ O2, bf16* __restrict__ O3,
    int lda, int ldb, int ldo, int K, long bSlice,
    long aZ1, long aZ2, long bZ1, long bZ2, long oZ1, long oZ2, int zoff)
{
  constexpr int WTM = BM / 2, WTN = BN / 2, FM = WTM / 16, FN = WTN / 16;
  constexpr int RA = (KW == 3) ? BM + 16 : BM;
  constexpr int ACH = RA / 16;         // 1KB chunks for A
  constexpr int BCHS = BN / 16;        // 1KB chunks per B kw-slice
  constexpr int TCH = ACH + KW * BCHS; // chunks per pipeline buffer
  __shared__ __align__(1024) bf16 sBuf[2][TCH * 512];

  const int tid = threadIdx.x;
  const int zl = blockIdx.z, zg = zl + zoff;
  const int zb = zg / ZD, zh = zg % ZD;
  const long aOff = AZL ? (long)zl * aZ1 : (long)zb * aZ1 + (long)zh * aZ2;
  const long bOff = (long)zb * bZ1 + (long)zh * bZ2;
  const long oOff = OZL ? (long)zl * oZ1 : (long)zb * oZ1 + (long)zh * oZ2;
  const int m0 = blockIdx.x * BM, n0 = blockIdx.y * BN;
  const bf16* Ab = A + aOff + (long)m0 * lda;
  const bf16* Bb = Bw + bOff + (long)n0 * ldb;

  const int wid = tid >> 6, lane = tid & 63;
  const int wm = wid >> 1, wn = wid & 1;
  const int l16 = lane & 15, q4 = lane >> 4;

  f32x4 acc[FM][FN] = {};

  auto STAGE = [&](int k0, int buf) {
    char* sa = (char*)sBuf[buf];
    stage_rows((const char*)(Ab + k0), (long)lda * 2, sa, ACH, tid);
    #pragma unroll
    for (int kw = 0; kw < KW; ++kw)
      stage_rows((const char*)(Bb + (long)kw * bSlice + k0), (long)ldb * 2,
                 sa + (ACH + kw * BCHS) * 1024, BCHS, tid);
  };

  auto COMPUTE = [&](int buf) {
    const char* sa = (const char*)sBuf[buf];
    const char* sb = sa + ACH * 1024;
    #pragma unroll
    for (int kw = 0; kw < KW; ++kw) {
      bf16x8 af[FM], bfr[FN];
      #pragma unroll
      for (int fm = 0; fm < FM; ++fm) {
        int row = wm * WTM + fm * 16 + l16 + (KW == 3 ? kw : 0);
        unsigned ad = (unsigned)(row * 64 + q4 * 16);
        ad ^= ((ad >> 7) & 3u) << 4;
        af[fm] = *(const bf16x8*)(sa + ad);
      }
      #pragma unroll
      for (int fn = 0; fn < FN; ++fn) {
        int rn = wn * WTN + fn * 16 + l16;
        unsigned bd = (unsigned)(rn * 64 + q4 * 16);
        bd ^= ((bd >> 7) & 3u) << 4;
        bfr[fn] = *(const bf16x8*)(sb + kw * BCHS * 1024 + bd);
      }
      #pragma unroll
      for (int fm = 0; fm < FM; ++fm)
        #pragma unroll
        for (int fn = 0; fn < FN; ++fn)
          acc[fm][fn] = __builtin_amdgcn_mfma_f32_16x16x32_bf16(af[fm], bfr[fn],
                                                                acc[fm][fn], 0, 0, 0);
    }
  };

  // 2-phase pipeline: prefetch next tile before computing current.
  STAGE(0, 0);
  __syncthreads();
  int cur = 0;
  for (int k0 = 32; k0 < K; k0 += 32) {
    STAGE(k0, cur ^ 1);
    COMPUTE(cur);
    __syncthreads();          // drains vmcnt (prefetch) + lgkm, flips buffer
    cur ^= 1;
  }
  COMPUTE(cur);

  // epilogue: C/D layout col=lane&15, row=(lane>>4)*4+i  [m89-verified]
  #pragma unroll
  for (int fn = 0; fn < FN; ++fn) {
    const int nl = n0 + wn * WTN + fn * 16 + l16;
    const float bv = (EPI == 1 || bias == nullptr) ? 0.f : bias[nl];
    #pragma unroll
    for (int fm = 0; fm < FM; ++fm) {
      const int mb = m0 + wm * WTM + fm * 16 + q4 * 4;
      f32x4 v = acc[fm][fn];
      float vals[4];
      #pragma unroll
      for (int i = 0; i < 4; ++i) {
        float t = v[i] + bv;
        if (RELU) t = fmaxf(t, 0.f);
        if (MASKM) t *= mask[(long)zb * T + mb + i];
        vals[i] = t;
      }
      if constexpr (EPI == 1) {
        f16* dst = (f16*)O + oOff;
        #pragma unroll
        for (int i = 0; i < 4; ++i)
          dst[(long)(mb + i) * ldo + nl] = (f16)(vals[i] * SCALE);
      } else if constexpr (EPI == 2) {
        if (nl < 1024) {
          bf16* dst = (nl < 512 ? O : O2) + oOff + (nl & 511);
          #pragma unroll
          for (int i = 0; i < 4; ++i)
            dst[(long)(mb + i) * C] = (bf16)vals[i];
        } else {
          bf16x4v tv;
          #pragma unroll
          for (int i = 0; i < 4; ++i) tv[i] = (bf16)vals[i];
          *(bf16x4v*)(O3 + oOff + (long)(nl - 1024) * T + mb) = tv;
        }
      } else {
        bf16* dst = O + oOff;
        #pragma unroll
        for (int i = 0; i < 4; ++i)
          dst[(long)(mb + i) * ldo + nl] = (bf16)vals[i];
      }
    }
  }
}

// ---------------- RoPE table ----------------
__global__ __launch_bounds__(256) void rope_tab_kernel(float* __restrict__ cosT,
                                                       float* __restrict__ sinT) {
  int idx = blockIdx.x * 256 + threadIdx.x;
  if (idx >= T * 16) return;
  int t = idx >> 4, j = idx & 15;
  float theta = powf(10000.f, -(float)j / 16.f);
  float s, c;
  sincosf((float)t * theta, &s, &c);
  cosT[idx] = c;
  sinT[idx] = s;
}

// ---------------- RoPE on bf16 q,k in [b][t][C] layout ----------------
__global__ __launch_bounds__(256) void rope_kernel(bf16* __restrict__ q, bf16* __restrict__ k,
                                                   const float* __restrict__ cosT,
                                                   const float* __restrict__ sinT) {
  int idx = blockIdx.x * 256 + threadIdx.x;   // B*T*H*16 = 2^19
  int j = idx & 15, h = (idx >> 4) & 7, t = (idx >> 7) & 1023, b = idx >> 17;
  long base = ((long)b * T + t) * C + h * 64 + j;
  float cv = cosT[t * 16 + j], sv = sinT[t * 16 + j];
  float a = (float)q[base], b2 = (float)q[base + 16];
  q[base] = (bf16)(a * cv - b2 * sv);
  q[base + 16] = (bf16)(b2 * cv + a * sv);
  a = (float)k[base]; b2 = (float)k[base + 16];
  k[base] = (bf16)(a * cv - b2 * sv);
  k[base + 16] = (bf16)(b2 * cv + a * sv);
}

// ---------------- in-place softmax: f16 scores -> bf16 probs ----------------
__global__ __launch_bounds__(256) void softmax_kernel(bf16* __restrict__ sp,
                                                      const float* __restrict__ mask, int zoff) {
  const long row = blockIdx.x;                 // zl*T + t
  const int zl = (int)(row >> 10), t = (int)(row & 1023);
  const int b = (zl + zoff) >> 3;
  const int tid = threadIdx.x;
  const f16* src = (const f16*)sp + row * T;
  f16x4v v = *(const f16x4v*)(src + tid * 4);
  const float mt = mask[(long)b * T + t];
  float sc[4];
  #pragma unroll
  for (int i = 0; i < 4; ++i) {
    float ms = mask[(long)b * T + tid * 4 + i];
    sc[i] = (mt * ms > 0.f) ? (float)v[i] : -10000.f;
  }
  __shared__ float red[256];
  float mx = fmaxf(fmaxf(sc[0], sc[1]), fmaxf(sc[2], sc[3]));
  red[tid] = mx; __syncthreads();
  for (int s = 128; s > 0; s >>= 1) {
    if (tid < s) red[tid] = fmaxf(red[tid], red[tid + s]);
    __syncthreads();
  }
  mx = red[0]; __syncthreads();
  float e[4], ssum = 0.f;
  #pragma unroll
  for (int i = 0; i < 4; ++i) { e[i] = __expf(sc[i] - mx); ssum += e[i]; }
  red[tid] = ssum; __syncthreads();
  for (int s = 128; s > 0; s >>= 1) {
    if (tid < s) red[tid] += red[tid + s];
    __syncthreads();
  }
  float inv = 1.f / red[0];
  bf16x4v p;
  #pragma unroll
  for (int i = 0; i < 4; ++i) p[i] = (bf16)(e[i] * inv);
  *(bf16x4v*)((bf16*)sp + row * T + tid * 4) = p;
}

// ---------------- fused residual + LayerNorm over contiguous C ----------------
__global__ __launch_bounds__(256) void ln_kernel(
    const float* __restrict__ x, const bf16* __restrict__ y,
    const float* __restrict__ gamma, const float* __restrict__ beta,
    const float* __restrict__ mask, int maskA, int maskY,
    float* __restrict__ xout, bf16* __restrict__ xm)
{
  const int w = threadIdx.x >> 6, lane = threadIdx.x & 63;
  const long row = (long)blockIdx.x * 4 + w;     // b*T + t
  const int b = (int)(row >> 10), t = (int)(row & 1023);
  const float* xr = x + row * C;
  const bf16* yr = y + row * C;
  const float m = mask[(long)b * T + t];
  const float fa = maskA ? m : 1.f, fy = maskY ? m : 1.f;
  float4 x0 = *(const float4*)(xr + lane * 8);
  float4 x1 = *(const float4*)(xr + lane * 8 + 4);
  bf16x8 yv = *(const bf16x8*)(yr + lane * 8);
  float vals[8] = {x0.x, x0.y, x0.z, x0.w, x1.x, x1.y, x1.z, x1.w};
  float sum = 0.f, sq = 0.f;
  #pragma unroll
  for (int i = 0; i < 8; ++i) {
    vals[i] = vals[i] * fa + (float)yv[i] * fy;
    sum += vals[i]; sq += vals[i] * vals[i];
  }
  #pragma unroll
  for (int s = 1; s < 64; s <<= 1) {
    sum += __shfl_xor(sum, s, 64);
    sq  += __shfl_xor(sq, s, 64);
  }
  float mean = sum * (1.f / C);
  float rstd = rsqrtf(sq * (1.f / C) - mean * mean + EPS);
  float4 g0 = *(const float4*)(gamma + lane * 8), g1v = *(const float4*)(gamma + lane * 8 + 4);
  float4 b0 = *(const float4*)(beta + lane * 8),  b1v = *(const float4*)(beta + lane * 8 + 4);
  float gg[8] = {g0.x, g0.y, g0.z, g0.w, g1v.x, g1v.y, g1v.z, g1v.w};
  float bb[8] = {b0.x, b0.y, b0.z, b0.w, b1v.x, b1v.y, b1v.z, b1v.w};
  float o[8]; bf16x8 xmv;
  #pragma unroll
  for (int i = 0; i < 8; ++i) {
    o[i] = (vals[i] - mean) * rstd * gg[i] + bb[i];
    xmv[i] = (bf16)(o[i] * m);
  }
  *(float4*)(xout + row * C + lane * 8)     = make_float4(o[0], o[1], o[2], o[3]);
  *(float4*)(xout + row * C + lane * 8 + 4) = make_float4(o[4], o[5], o[6], o[7]);
  *(bf16x8*)(xm + ((long)b * TP + t + 1) * C + lane * 8) = xmv;
}

// ---------------- transposes [b][C][T] <-> [b][t][C] ----------------
__global__ __launch_bounds__(256) void transpose_in_kernel(const float* __restrict__ xin,
                                                           const float* __restrict__ mask,
                                                           float* __restrict__ x,
                                                           bf16* __restrict__ xm) {
  __shared__ float tile[32][33];
  int tx = threadIdx.x, ty = threadIdx.y;
  int t0 = blockIdx.x * 32, c0 = blockIdx.y * 32, b = blockIdx.z;
  #pragma unroll
  for (int i = 0; i < 4; ++i)
    tile[ty + i * 8][tx] = xin[((long)b * C + c0 + ty + i * 8) * T + t0 + tx];
  __syncthreads();
  #pragma unroll
  for (int i = 0; i < 4; ++i) {
    int t = t0 + ty + i * 8;
    float val = tile[tx][ty + i * 8];
    float m = mask[(long)b * T + t];
    x[((long)b * T + t) * C + c0 + tx] = val;
    xm[((long)b * TP + t + 1) * C + c0 + tx] = (bf16)(val * m);
  }
}

__global__ __launch_bounds__(256) void transpose_out_kernel(const float* __restrict__ x,
                                                            const float* __restrict__ mask,
                                                            float* __restrict__ out) {
  __shared__ float tile[32][33];
  int tx = threadIdx.x, ty = threadIdx.y;
  int t0 = blockIdx.x * 32, c0 = blockIdx.y * 32, b = blockIdx.z;
  #pragma unroll
  for (int i = 0; i < 4; ++i)
    tile[ty + i * 8][tx] = x[((long)b * T + t0 + ty + i * 8) * C + c0 + tx];
  __syncthreads();
  #pragma unroll
  for (int i = 0; i < 4; ++i) {
    int t = t0 + tx;
    out[((long)b * C + c0 + ty + i * 8) * T + t] = tile[tx][ty + i * 8] * mask[(long)b * T + t];
  }
}

// ---------------- zero halo rows of padded activation buffers ----------------
__global__ __launch_bounds__(256) void zero_pads_kernel(bf16* __restrict__ xm, bf16* __restrict__ h) {
  long idx = (long)blockIdx.x * 256 + threadIdx.x;
  const long n1 = (long)B * 18 * C;
  const long n2 = (long)B * 18 * F;
  if (idx < n1) {
    int c = (int)(idx % C); int r = (int)((idx / C) % 18); int b = (int)(idx / (18L * C));
    int p = (r == 0) ? 0 : (T + r);
    xm[((long)b * TP + p) * C + c] = (bf16)0.f;
  } else if (idx < n1 + n2) {
    long j = idx - n1;
    int c = (int)(j % F); int r = (int)((j / F) % 18); int b = (int)(j / (18L * F));
    int p = (r == 0) ? 0 : (T + r);
    h[((long)b * TP + p) * F + c] = (bf16)0.f;
  }
}

// ---------------- weight fp32 -> bf16 with [KW][N][K] split ----------------
__global__ __launch_bounds__(256) void cvt_w_kernel(const float* __restrict__ src,
                                                    bf16* __restrict__ dst,
                                                    int N, int Kd, int KW, long total) {
  long idx = (long)blockIdx.x * 256 + threadIdx.x;
  if (idx >= total) return;
  int c = (int)(idx % Kd);
  long r = idx / Kd;
  int n = (int)(r % N);
  int k = (int)(r / N);
  dst[idx] = (bf16)src[((long)n * Kd + c) * KW + k];
}

__global__ __launch_bounds__(256) void catb_kernel(const float* __restrict__ a,
                                                   const float* __restrict__ b,
                                                   const float* __restrict__ c,
                                                   float* __restrict__ dst) {
  int i = blockIdx.x * 256 + threadIdx.x;
  if (i < 512) dst[i] = a[i];
  else if (i < 1024) dst[i] = b[i - 512];
  else if (i < 1536) dst[i] = c[i - 1024];
}

// ---------------------------------------------------------------------------
extern "C" void kernel_launch(void* const* d_in, const int* in_sizes, int n_in,
                              void* d_out, int out_size, void* d_ws, size_t ws_size,
                              hipStream_t stream)
{
  const float* xin = (const float*)d_in[0];
  const float* msk = (const float*)d_in[1];
  const float* Wq  = (const float*)d_in[2];
  const float* bq  = (const float*)d_in[3];
  const float* Wk  = (const float*)d_in[4];
  const float* bk  = (const float*)d_in[5];
  const float* Wv  = (const float*)d_in[6];
  const float* bv  = (const float*)d_in[7];
  const float* Wo  = (const float*)d_in[8];
  const float* bo  = (const float*)d_in[9];
  const float* g1  = (const float*)d_in[10];
  const float* be1 = (const float*)d_in[11];
  const float* W1  = (const float*)d_in[12];
  const float* c1  = (const float*)d_in[13];
  const float* W2  = (const float*)d_in[14];
  const float* c2  = (const float*)d_in[15];
  const float* g2  = (const float*)d_in[16];
  const float* be2 = (const float*)d_in[17];

  // ---- workspace carve (1KB aligned) ----
  size_t off = 0;
  char* base = (char*)d_ws;
  auto alloc = [&](size_t bytes) -> char* {
    char* r = base + off;
    off = (off + bytes + 1023) & ~(size_t)1023;
    return r;
  };
  float* x     = (float*)alloc((size_t)B * T * C * 4);
  float* ropeC = (float*)alloc((size_t)T * 16 * 4);
  float* ropeS = (float*)alloc((size_t)T * 16 * 4);
  float* bqkv  = (float*)alloc(1536 * 4);
  bf16* xm  = (bf16*)alloc((size_t)B * TP * C * 2);
  bf16* hb  = (bf16*)alloc((size_t)B * TP * F * 2);
  bf16* q   = (bf16*)alloc((size_t)B * T * C * 2);
  bf16* k   = (bf16*)alloc((size_t)B * T * C * 2);
  bf16* vT  = (bf16*)alloc((size_t)B * T * C * 2);
  bf16* o   = (bf16*)alloc((size_t)B * T * C * 2);
  bf16* yb  = (bf16*)alloc((size_t)B * T * C * 2);
  bf16* wqkv = (bf16*)alloc((size_t)3 * C * C * 2);
  bf16* wo   = (bf16*)alloc((size_t)C * C * 2);
  bf16* w1b  = (bf16*)alloc((size_t)3 * F * C * 2);
  bf16* w2b  = (bf16*)alloc((size_t)3 * C * F * 2);
  size_t fixedBytes = off;
  bool fullB = (ws_size >= fixedBytes + (size_t)32 * T * T * 2 + 2048);
  int zmax = fullB ? 32 : 8;
  bf16* scoresP = (bf16*)alloc((size_t)zmax * T * T * 2);
  (void)in_sizes; (void)n_in; (void)out_size;

  // ---- prologue ----
  {
    long tot = (long)B * 18 * (C + F);
    zero_pads_kernel<<<(int)((tot + 255) / 256), 256, 0, stream>>>(xm, hb);
  }
  transpose_in_kernel<<<dim3(T / 32, C / 32, B), dim3(32, 8), 0, stream>>>(xin, msk, x, xm);
  rope_tab_kernel<<<(T * 16 + 255) / 256, 256, 0, stream>>>(ropeC, ropeS);

  for (int i = 0; i < L; ++i) {
    const float* Wq_i = Wq + (size_t)i * C * C;
    const float* Wk_i = Wk + (size_t)i * C * C;
    const float* Wv_i = Wv + (size_t)i * C * C;
    const float* Wo_i = Wo + (size_t)i * C * C;
    const float* W1_i = W1 + (size_t)i * F * C * 3;
    const float* W2_i = W2 + (size_t)i * C * F * 3;

    // weight conversion (bf16, per-layer reuse)
    long tq = (long)C * C;
    cvt_w_kernel<<<(int)((tq + 255) / 256), 256, 0, stream>>>(Wq_i, wqkv, C, C, 1, tq);
    cvt_w_kernel<<<(int)((tq + 255) / 256), 256, 0, stream>>>(Wk_i, wqkv + tq, C, C, 1, tq);
    cvt_w_kernel<<<(int)((tq + 255) / 256), 256, 0, stream>>>(Wv_i, wqkv + 2 * tq, C, C, 1, tq);
    cvt_w_kernel<<<(int)((tq + 255) / 256), 256, 0, stream>>>(Wo_i, wo, C, C, 1, tq);
    long t1 = 3L * F * C;
    cvt_w_kernel<<<(int)((t1 + 255) / 256), 256, 0, stream>>>(W1_i, w1b, F, C, 3, t1);
    cvt_w_kernel<<<(int)((t1 + 255) / 256), 256, 0, stream>>>(W2_i, w2b, C, F, 3, t1);
    catb_kernel<<<6, 256, 0, stream>>>(bq + (size_t)i * C, bk + (size_t)i * C, bv + (size_t)i * C, bqkv);

    // fused QKV projection (N=1536), v stored transposed
    gemm_kernel<64, 128, 1, 2, false, false, 1, false, false, 4>
        <<<dim3(16, 12, B), 256, 0, stream>>>(
        xm + C, wqkv, bqkv, msk, q, k, vT,
        C, C, C, C, 0,
        (long)TP * C, 0, 0, 0, (long)T * C, 0, 0);

    rope_kernel<<<(B * T * H * 16) / 256, 256, 0, stream>>>(q, k, ropeC, ropeS);

    // attention: scores (f16) -> softmax (bf16 in place) -> PV
    int nPass = fullB ? 1 : B;
    int zcnt = fullB ? 32 : 8;
    for (int p = 0; p < nPass; ++p) {
      int zoff = fullB ? 0 : p * 8;
      gemm_kernel<128, 128, 1, 1, false, false, 8, false, true, 2>
          <<<dim3(8, 8, zcnt), 256, 0, stream>>>(
          q, k, nullptr, msk, scoresP, nullptr, nullptr,
          C, C, T, 64, 0,
          (long)T * C, 64, (long)T * C, 64, (long)T * T, 0, zoff);
      softmax_kernel<<<zcnt * T, 256, 0, stream>>>(scoresP, msk, zoff);
      gemm_kernel<64, 64, 1, 0, false, false, 8, true, false, 4>
          <<<dim3(16, 1, zcnt), 256, 0, stream>>>(
          scoresP, vT, nullptr, msk, o, nullptr, nullptr,
          T, T, C, T, 0,
          (long)T * T, 0, (long)C * T, (long)64 * T, (long)T * C, 64, zoff);
    }

    // O projection (batch flattened: M = B*T)
    gemm_kernel<64, 64, 1, 0, false, false, 1, false, false, 4>
        <<<dim3(64, 8, 1), 256, 0, stream>>>(
        o, wo, bo + (size_t)i * C, msk, yb, nullptr, nullptr,
        C, C, C, C, 0,
        0, 0, 0, 0, 0, 0, 0);

    ln_kernel<<<B * T / 4, 256, 0, stream>>>(x, yb, g1 + (size_t)i * C, be1 + (size_t)i * C,
                                             msk, 1, 0, x, xm);

    // FFN conv1 (K=3, relu, masked output)
    gemm_kernel<128, 64, 3, 0, true, true, 1, false, false, 3>
        <<<dim3(8, 32, B), 256, 0, stream>>>(
        xm, w1b, c1 + (size_t)i * F, msk, hb + F, nullptr, nullptr,
        C, C, F, C, (long)F * C,
        (long)TP * C, 0, 0, 0, (long)TP * F, 0, 0);

    // FFN conv2 (K=3)
    gemm_kernel<64, 64, 3, 0, false, false, 1, false, false, 4>
        <<<dim3(16, 8, B), 256, 0, stream>>>(
        hb, w2b, c2 + (size_t)i * C, msk, yb, nullptr, nullptr,
        F, F, C, F, (long)C * F,
        (long)TP * F, 0, 0, 0, (long)T * C, 0, 0);

    ln_kernel<<<B * T / 4, 256, 0, stream>>>(x, yb, g2 + (size_t)i * C, be2 + (size_t)i * C,
                                             msk, 0, 1, x, xm);
  }

  transpose_out_kernel<<<dim3(T / 32, C / 32, B), dim3(32, 8), 0, stream>>>(x, msk, (float*)d_out);
}

// Round 4
// 1012.438 us; speedup vs baseline: 13.0400x; 1.3052x over previous
//
#include <hip/hip_runtime.h>

typedef __bf16 bf16;
typedef __bf16 bf16x8 __attribute__((ext_vector_type(8)));
typedef __bf16 bf16x4v __attribute__((ext_vector_type(4)));
typedef float f32x4 __attribute__((ext_vector_type(4)));

constexpr int B = 4, C = 512, T = 1024, H = 8, F = 2048, L = 6;
constexpr int TP = T + 18;               // padded rows: row0 = zero, rows T+1..T+17 zero
constexpr float SCALE = 0.125f, EPS = 1e-4f;

// ---------------------------------------------------------------------------
// global -> LDS staging, 64B rows (GEMM tiles: 32 bf16 k-slice per row)
// LDS linear; swizzle applied on the per-lane GLOBAL source (involution),
// matched by the same XOR on the ds_read side.
// ---------------------------------------------------------------------------
__device__ __forceinline__ void stage_rows(const char* g, long strideB, char* lds,
                                           int nChunks, int tid) {
  const int wave = tid >> 6, lane = tid & 63;
  for (int c = wave; c < nChunks; c += 4) {
    int row = (c << 4) + (lane >> 2);
    int kq = (lane & 3) ^ ((row >> 1) & 3);
    const char* src = g + (long)row * strideB + kq * 16;
    char* dst = lds + ((long)c << 10);
    __builtin_amdgcn_global_load_lds((const __attribute__((address_space(1))) void*)src,
                                     (__attribute__((address_space(3))) void*)dst,
                                     16, 0, 0);
  }
}

// 128B rows (flash tiles: 64 bf16 per row). LDS[row][slot16] = G[row][slot ^ (row&7)].
__device__ __forceinline__ void stage_rows128(const char* g, long strideB, char* lds,
                                              int nChunks, int tid) {
  const int wave = tid >> 6, lane = tid & 63;
  for (int c = wave; c < nChunks; c += 4) {
    int row = (c << 3) + (lane >> 3);
    int kq = (lane & 7) ^ ((lane >> 3) & 7);
    const char* src = g + (long)row * strideB + kq * 16;
    char* dst = lds + ((long)c << 10);
    __builtin_amdgcn_global_load_lds((const __attribute__((address_space(1))) void*)src,
                                     (__attribute__((address_space(3))) void*)dst,
                                     16, 0, 0);
  }
}

// ---------------------------------------------------------------------------
// NT GEMM, 2-phase prefetch double-buffered LDS.
// D[m][n] = sum_k A[m][k] * Bw[n][k]  (+ kw-shifted A rows for KW=3)
// EPI: 0 = bf16 [m][ldo] (+bias, relu, maskM opts)
//      2 = QKV split: n<512 -> O(q), <1024 -> O2(k), else O3 = vT[n-1024][m]
// ---------------------------------------------------------------------------
template <int BM, int BN, int KW, int EPI, bool RELU, bool MASKM, int ZD,
          bool AZL, bool OZL, int MINW>
__global__ __launch_bounds__(256, MINW) void gemm_kernel(
    const bf16* __restrict__ A, const bf16* __restrict__ Bw,
    const float* __restrict__ bias, const float* __restrict__ mask,
    bf16* __restrict__ O, bf16* __restrict__ O2, bf16* __restrict__ O3,
    int lda, int ldb, int ldo, int K, long bSlice,
    long aZ1, long aZ2, long bZ1, long bZ2, long oZ1, long oZ2, int zoff)
{
  constexpr int WTM = BM / 2, WTN = BN / 2, FM = WTM / 16, FN = WTN / 16;
  constexpr int RA = (KW == 3) ? BM + 16 : BM;
  constexpr int ACH = RA / 16;
  constexpr int BCHS = BN / 16;
  constexpr int TCH = ACH + KW * BCHS;
  __shared__ __align__(1024) bf16 sBuf[2][TCH * 512];

  const int tid = threadIdx.x;
  const int zl = blockIdx.z, zg = zl + zoff;
  const int zb = zg / ZD, zh = zg % ZD;
  const long aOff = AZL ? (long)zl * aZ1 : (long)zb * aZ1 + (long)zh * aZ2;
  const long bOff = (long)zb * bZ1 + (long)zh * bZ2;
  const long oOff = OZL ? (long)zl * oZ1 : (long)zb * oZ1 + (long)zh * oZ2;
  const int m0 = blockIdx.x * BM, n0 = blockIdx.y * BN;
  const bf16* Ab = A + aOff + (long)m0 * lda;
  const bf16* Bb = Bw + bOff + (long)n0 * ldb;

  const int wid = tid >> 6, lane = tid & 63;
  const int wm = wid >> 1, wn = wid & 1;
  const int l16 = lane & 15, q4 = lane >> 4;

  f32x4 acc[FM][FN] = {};

  auto STAGE = [&](int k0, int buf) {
    char* sa = (char*)sBuf[buf];
    stage_rows((const char*)(Ab + k0), (long)lda * 2, sa, ACH, tid);
    #pragma unroll
    for (int kw = 0; kw < KW; ++kw)
      stage_rows((const char*)(Bb + (long)kw * bSlice + k0), (long)ldb * 2,
                 sa + (ACH + kw * BCHS) * 1024, BCHS, tid);
  };

  auto COMPUTE = [&](int buf) {
    const char* sa = (const char*)sBuf[buf];
    const char* sb = sa + ACH * 1024;
    #pragma unroll
    for (int kw = 0; kw < KW; ++kw) {
      bf16x8 af[FM], bfr[FN];
      #pragma unroll
      for (int fm = 0; fm < FM; ++fm) {
        int row = wm * WTM + fm * 16 + l16 + (KW == 3 ? kw : 0);
        unsigned ad = (unsigned)(row * 64 + q4 * 16);
        ad ^= ((ad >> 7) & 3u) << 4;
        af[fm] = *(const bf16x8*)(sa + ad);
      }
      #pragma unroll
      for (int fn = 0; fn < FN; ++fn) {
        int rn = wn * WTN + fn * 16 + l16;
        unsigned bd = (unsigned)(rn * 64 + q4 * 16);
        bd ^= ((bd >> 7) & 3u) << 4;
        bfr[fn] = *(const bf16x8*)(sb + kw * BCHS * 1024 + bd);
      }
      #pragma unroll
      for (int fm = 0; fm < FM; ++fm)
        #pragma unroll
        for (int fn = 0; fn < FN; ++fn)
          acc[fm][fn] = __builtin_amdgcn_mfma_f32_16x16x32_bf16(af[fm], bfr[fn],
                                                                acc[fm][fn], 0, 0, 0);
    }
  };

  STAGE(0, 0);
  __syncthreads();
  int cur = 0;
  for (int k0 = 32; k0 < K; k0 += 32) {
    STAGE(k0, cur ^ 1);
    COMPUTE(cur);
    __syncthreads();
    cur ^= 1;
  }
  COMPUTE(cur);

  #pragma unroll
  for (int fn = 0; fn < FN; ++fn) {
    const int nl = n0 + wn * WTN + fn * 16 + l16;
    const float bv = (bias == nullptr) ? 0.f : bias[nl];
    #pragma unroll
    for (int fm = 0; fm < FM; ++fm) {
      const int mb = m0 + wm * WTM + fm * 16 + q4 * 4;
      f32x4 v = acc[fm][fn];
      float vals[4];
      #pragma unroll
      for (int i = 0; i < 4; ++i) {
        float t = v[i] + bv;
        if (RELU) t = fmaxf(t, 0.f);
        if (MASKM) t *= mask[(long)zb * T + mb + i];
        vals[i] = t;
      }
      if constexpr (EPI == 2) {
        if (nl < 1024) {
          bf16* dst = (nl < 512 ? O : O2) + oOff + (nl & 511);
          #pragma unroll
          for (int i = 0; i < 4; ++i)
            dst[(long)(mb + i) * C] = (bf16)vals[i];
        } else {
          bf16x4v tv;
          #pragma unroll
          for (int i = 0; i < 4; ++i) tv[i] = (bf16)vals[i];
          *(bf16x4v*)(O3 + oOff + (long)(nl - 1024) * T + mb) = tv;
        }
      } else {
        bf16* dst = O + oOff;
        #pragma unroll
        for (int i = 0; i < 4; ++i)
          dst[(long)(mb + i) * ldo + nl] = (bf16)vals[i];
      }
    }
  }
}

// ---------------------------------------------------------------------------
// Flash attention: one block = 64 q-rows x one (b,h). 4 waves x 16 q-rows.
// K/V 64-wide tiles double-buffered in LDS; online softmax; P via per-wave LDS.
// ---------------------------------------------------------------------------
__global__ __launch_bounds__(256, 3) void flash_kernel(
    const bf16* __restrict__ q, const bf16* __restrict__ k,
    const bf16* __restrict__ vT, const float* __restrict__ mask,
    bf16* __restrict__ o)
{
  __shared__ __align__(1024) char sQ[64 * 128];
  __shared__ __align__(1024) char sK[2][64 * 128];
  __shared__ __align__(1024) char sV[2][64 * 128];
  __shared__ __align__(1024) char sP[4][16 * 128];

  const int tid = threadIdx.x;
  const int w = tid >> 6, lane = tid & 63;
  const int l16 = lane & 15, q4 = lane >> 4;
  const int q0 = blockIdx.x * 64;
  const int bh = blockIdx.y;
  const int b = bh >> 3, h = bh & 7;

  const bf16* qb = q + ((long)b * T + q0) * C + h * 64;
  const bf16* kb = k + (long)b * T * C + h * 64;
  const bf16* vb = vT + (long)b * C * T + (long)h * 64 * T;

  // prologue: stage Q tile + KV tile 0
  stage_rows128((const char*)qb, (long)C * 2, sQ, 8, tid);
  stage_rows128((const char*)kb, (long)C * 2, sK[0], 8, tid);
  stage_rows128((const char*)vb, (long)T * 2, sV[0], 8, tid);
  __syncthreads();

  // Q fragments into registers: row = w*16 + l16
  bf16x8 af_q[2];
  {
    const int r = w * 16 + l16;
    #pragma unroll
    for (int kk = 0; kk < 2; ++kk) {
      unsigned off = (unsigned)(kk * 64 + q4 * 16) ^ ((unsigned)(r & 7) << 4);
      af_q[kk] = *(const bf16x8*)(sQ + r * 128 + off);
    }
  }

  float mq[4];
  #pragma unroll
  for (int i = 0; i < 4; ++i)
    mq[i] = mask[(long)b * T + q0 + w * 16 + q4 * 4 + i];

  f32x4 accO[4] = {};
  float mrun[4] = {-1e30f, -1e30f, -1e30f, -1e30f};
  float lrun[4] = {0.f, 0.f, 0.f, 0.f};
  char* sPw = sP[w];

  int cur = 0;
  for (int it = 0; it < 16; ++it) {
    if (it < 15) {
      stage_rows128((const char*)(kb + (long)(it + 1) * 64 * C), (long)C * 2, sK[cur ^ 1], 8, tid);
      stage_rows128((const char*)(vb + (it + 1) * 64), (long)T * 2, sV[cur ^ 1], 8, tid);
    }
    // S = Q . K^T  (m = 16 q rows, n = 64 kv)
    f32x4 s[4] = {};
    #pragma unroll
    for (int kk = 0; kk < 2; ++kk) {
      #pragma unroll
      for (int fn = 0; fn < 4; ++fn) {
        const int rn = fn * 16 + l16;
        unsigned off = (unsigned)(kk * 64 + q4 * 16) ^ ((unsigned)(rn & 7) << 4);
        bf16x8 kf = *(const bf16x8*)(sK[cur] + rn * 128 + off);
        s[fn] = __builtin_amdgcn_mfma_f32_16x16x32_bf16(af_q[kk], kf, s[fn], 0, 0, 0);
      }
    }
    // mask + scale
    float mk[4];
    #pragma unroll
    for (int fn = 0; fn < 4; ++fn)
      mk[fn] = mask[(long)b * T + it * 64 + fn * 16 + l16];
    float sv[4][4];
    #pragma unroll
    for (int fn = 0; fn < 4; ++fn)
      #pragma unroll
      for (int i = 0; i < 4; ++i) {
        float xval = s[fn][i] * SCALE;
        sv[fn][i] = (mq[i] * mk[fn] > 0.f) ? xval : -10000.f;
      }
    // online softmax update
    float cor[4];
    #pragma unroll
    for (int i = 0; i < 4; ++i) {
      float m0 = fmaxf(fmaxf(sv[0][i], sv[1][i]), fmaxf(sv[2][i], sv[3][i]));
      #pragma unroll
      for (int st = 1; st < 16; st <<= 1) m0 = fmaxf(m0, __shfl_xor(m0, st, 64));
      float mnew = fmaxf(mrun[i], m0);
      cor[i] = __expf(mrun[i] - mnew);
      mrun[i] = mnew;
    }
    float rs[4] = {0.f, 0.f, 0.f, 0.f};
    #pragma unroll
    for (int fn = 0; fn < 4; ++fn)
      #pragma unroll
      for (int i = 0; i < 4; ++i) {
        float p = __expf(sv[fn][i] - mrun[i]);
        rs[i] += p;
        const int row = q4 * 4 + i;
        unsigned off = (unsigned)((fn * 16 + l16) * 2) ^ ((unsigned)(row & 7) << 4);
        *(bf16*)(sPw + row * 128 + off) = (bf16)p;
      }
    #pragma unroll
    for (int i = 0; i < 4; ++i) {
      #pragma unroll
      for (int st = 1; st < 16; st <<= 1) rs[i] += __shfl_xor(rs[i], st, 64);
      lrun[i] = lrun[i] * cor[i] + rs[i];
    }
    #pragma unroll
    for (int fn = 0; fn < 4; ++fn)
      #pragma unroll
      for (int i = 0; i < 4; ++i) accO[fn][i] *= cor[i];
    // O += P . V   (A = P rows q, B = vT rows c, k = kv)
    #pragma unroll
    for (int kk = 0; kk < 2; ++kk) {
      unsigned poff = (unsigned)(kk * 64 + q4 * 16) ^ ((unsigned)(l16 & 7) << 4);
      bf16x8 pf = *(const bf16x8*)(sPw + l16 * 128 + poff);
      #pragma unroll
      for (int fn = 0; fn < 4; ++fn) {
        const int rn = fn * 16 + l16;
        unsigned off = (unsigned)(kk * 64 + q4 * 16) ^ ((unsigned)(rn & 7) << 4);
        bf16x8 vf = *(const bf16x8*)(sV[cur] + rn * 128 + off);
        accO[fn] = __builtin_amdgcn_mfma_f32_16x16x32_bf16(pf, vf, accO[fn], 0, 0, 0);
      }
    }
    __syncthreads();
    cur ^= 1;
  }

  // epilogue: o[(b*T + qrow)][h*64 + c]
  float linv[4];
  #pragma unroll
  for (int i = 0; i < 4; ++i) linv[i] = 1.f / lrun[i];
  #pragma unroll
  for (int fn = 0; fn < 4; ++fn)
    #pragma unroll
    for (int i = 0; i < 4; ++i)
      o[((long)b * T + q0 + w * 16 + q4 * 4 + i) * C + h * 64 + fn * 16 + l16] =
          (bf16)(accO[fn][i] * linv[i]);
}

// ---------------- RoPE table ----------------
__global__ __launch_bounds__(256) void rope_tab_kernel(float* __restrict__ cosT,
                                                       float* __restrict__ sinT) {
  int idx = blockIdx.x * 256 + threadIdx.x;
  if (idx >= T * 16) return;
  int t = idx >> 4, j = idx & 15;
  float theta = powf(10000.f, -(float)j / 16.f);
  float s, c;
  sincosf((float)t * theta, &s, &c);
  cosT[idx] = c;
  sinT[idx] = s;
}

// ---------------- RoPE on bf16 q,k in [b][t][C] layout ----------------
__global__ __launch_bounds__(256) void rope_kernel(bf16* __restrict__ q, bf16* __restrict__ k,
                                                   const float* __restrict__ cosT,
                                                   const float* __restrict__ sinT) {
  int idx = blockIdx.x * 256 + threadIdx.x;
  int j = idx & 15, h = (idx >> 4) & 7, t = (idx >> 7) & 1023, b = idx >> 17;
  long base = ((long)b * T + t) * C + h * 64 + j;
  float cv = cosT[t * 16 + j], sv = sinT[t * 16 + j];
  float a = (float)q[base], b2 = (float)q[base + 16];
  q[base] = (bf16)(a * cv - b2 * sv);
  q[base + 16] = (bf16)(b2 * cv + a * sv);
  a = (float)k[base]; b2 = (float)k[base + 16];
  k[base] = (bf16)(a * cv - b2 * sv);
  k[base + 16] = (bf16)(b2 * cv + a * sv);
}

// ---------------- fused residual + LayerNorm over contiguous C ----------------
__global__ __launch_bounds__(256) void ln_kernel(
    const float* __restrict__ x, const bf16* __restrict__ y,
    const float* __restrict__ gamma, const float* __restrict__ beta,
    const float* __restrict__ mask, int maskA, int maskY,
    float* __restrict__ xout, bf16* __restrict__ xm)
{
  const int w = threadIdx.x >> 6, lane = threadIdx.x & 63;
  const long row = (long)blockIdx.x * 4 + w;
  const int b = (int)(row >> 10), t = (int)(row & 1023);
  const float* xr = x + row * C;
  const bf16* yr = y + row * C;
  const float m = mask[(long)b * T + t];
  const float fa = maskA ? m : 1.f, fy = maskY ? m : 1.f;
  float4 x0 = *(const float4*)(xr + lane * 8);
  float4 x1 = *(const float4*)(xr + lane * 8 + 4);
  bf16x8 yv = *(const bf16x8*)(yr + lane * 8);
  float vals[8] = {x0.x, x0.y, x0.z, x0.w, x1.x, x1.y, x1.z, x1.w};
  float sum = 0.f, sq = 0.f;
  #pragma unroll
  for (int i = 0; i < 8; ++i) {
    vals[i] = vals[i] * fa + (float)yv[i] * fy;
    sum += vals[i]; sq += vals[i] * vals[i];
  }
  #pragma unroll
  for (int s = 1; s < 64; s <<= 1) {
    sum += __shfl_xor(sum, s, 64);
    sq  += __shfl_xor(sq, s, 64);
  }
  float mean = sum * (1.f / C);
  float rstd = rsqrtf(sq * (1.f / C) - mean * mean + EPS);
  float4 g0 = *(const float4*)(gamma + lane * 8), g1v = *(const float4*)(gamma + lane * 8 + 4);
  float4 b0 = *(const float4*)(beta + lane * 8),  b1v = *(const float4*)(beta + lane * 8 + 4);
  float gg[8] = {g0.x, g0.y, g0.z, g0.w, g1v.x, g1v.y, g1v.z, g1v.w};
  float bb[8] = {b0.x, b0.y, b0.z, b0.w, b1v.x, b1v.y, b1v.z, b1v.w};
  float o[8]; bf16x8 xmv;
  #pragma unroll
  for (int i = 0; i < 8; ++i) {
    o[i] = (vals[i] - mean) * rstd * gg[i] + bb[i];
    xmv[i] = (bf16)(o[i] * m);
  }
  *(float4*)(xout + row * C + lane * 8)     = make_float4(o[0], o[1], o[2], o[3]);
  *(float4*)(xout + row * C + lane * 8 + 4) = make_float4(o[4], o[5], o[6], o[7]);
  *(bf16x8*)(xm + ((long)b * TP + t + 1) * C + lane * 8) = xmv;
}

// ---------------- transposes [b][C][T] <-> [b][t][C] ----------------
__global__ __launch_bounds__(256) void transpose_in_kernel(const float* __restrict__ xin,
                                                           const float* __restrict__ mask,
                                                           float* __restrict__ x,
                                                           bf16* __restrict__ xm) {
  __shared__ float tile[32][33];
  int tx = threadIdx.x, ty = threadIdx.y;
  int t0 = blockIdx.x * 32, c0 = blockIdx.y * 32, b = blockIdx.z;
  #pragma unroll
  for (int i = 0; i < 4; ++i)
    tile[ty + i * 8][tx] = xin[((long)b * C + c0 + ty + i * 8) * T + t0 + tx];
  __syncthreads();
  #pragma unroll
  for (int i = 0; i < 4; ++i) {
    int t = t0 + ty + i * 8;
    float val = tile[tx][ty + i * 8];
    float m = mask[(long)b * T + t];
    x[((long)b * T + t) * C + c0 + tx] = val;
    xm[((long)b * TP + t + 1) * C + c0 + tx] = (bf16)(val * m);
  }
}

__global__ __launch_bounds__(256) void transpose_out_kernel(const float* __restrict__ x,
                                                            const float* __restrict__ mask,
                                                            float* __restrict__ out) {
  __shared__ float tile[32][33];
  int tx = threadIdx.x, ty = threadIdx.y;
  int t0 = blockIdx.x * 32, c0 = blockIdx.y * 32, b = blockIdx.z;
  #pragma unroll
  for (int i = 0; i < 4; ++i)
    tile[ty + i * 8][tx] = x[((long)b * T + t0 + ty + i * 8) * C + c0 + tx];
  __syncthreads();
  #pragma unroll
  for (int i = 0; i < 4; ++i) {
    int t = t0 + tx;
    out[((long)b * C + c0 + ty + i * 8) * T + t] = tile[tx][ty + i * 8] * mask[(long)b * T + t];
  }
}

// ---------------- zero halo rows of padded activation buffers ----------------
__global__ __launch_bounds__(256) void zero_pads_kernel(bf16* __restrict__ xm, bf16* __restrict__ h) {
  long idx = (long)blockIdx.x * 256 + threadIdx.x;
  const long n1 = (long)B * 18 * C;
  const long n2 = (long)B * 18 * F;
  if (idx < n1) {
    int c = (int)(idx % C); int r = (int)((idx / C) % 18); int b = (int)(idx / (18L * C));
    int p = (r == 0) ? 0 : (T + r);
    xm[((long)b * TP + p) * C + c] = (bf16)0.f;
  } else if (idx < n1 + n2) {
    long j = idx - n1;
    int c = (int)(j % F); int r = (int)((j / F) % 18); int b = (int)(j / (18L * F));
    int p = (r == 0) ? 0 : (T + r);
    h[((long)b * TP + p) * F + c] = (bf16)0.f;
  }
}

// ---------------- one-time all-layer weight conversions ----------------
// qkv: dst[i][slot*512+n][c] (x4 vectorized over c)
__global__ __launch_bounds__(256) void cvt_qkv_all(const float* __restrict__ Wq,
                                                   const float* __restrict__ Wk,
                                                   const float* __restrict__ Wv,
                                                   bf16* __restrict__ dst) {
  long idx = (long)blockIdx.x * 256 + threadIdx.x;   // L*3*C*C/4
  if (idx >= (long)L * 3 * C * C / 4) return;
  int c4 = (int)(idx & 127) * 4;
  int n = (int)((idx >> 7) & 511);
  int s2 = (int)(idx >> 16);
  int slot = s2 % 3, i = s2 / 3;
  const float* src = (slot == 0 ? Wq : slot == 1 ? Wk : Wv) + (long)i * C * C + (long)n * C + c4;
  float4 v = *(const float4*)src;
  bf16x4v d = {(bf16)v.x, (bf16)v.y, (bf16)v.z, (bf16)v.w};
  *(bf16x4v*)(dst + (((long)(i * 3 + slot) * 512 + n) * 512 + c4)) = d;
}

__global__ __launch_bounds__(256) void cvt_wo_all(const float* __restrict__ src,
                                                  bf16* __restrict__ dst) {
  long idx = (long)blockIdx.x * 256 + threadIdx.x;   // L*C*C/4
  if (idx >= (long)L * C * C / 4) return;
  float4 v = *(const float4*)(src + idx * 4);
  bf16x4v d = {(bf16)v.x, (bf16)v.y, (bf16)v.z, (bf16)v.w};
  *(bf16x4v*)(dst + idx * 4) = d;
}

// w1/w2: dst[i][k][n][c] = src[i][(n*Kd + c)*3 + k]
__global__ __launch_bounds__(256) void cvt_w3_all(const float* __restrict__ src,
                                                  bf16* __restrict__ dst, int N, int Kd) {
  long idx = (long)blockIdx.x * 256 + threadIdx.x;   // L*3*N*Kd
  long total = (long)L * 3 * N * Kd;
  if (idx >= total) return;
  int c = (int)(idx % Kd);
  long r = idx / Kd;
  int n = (int)(r % N);
  long r2 = r / N;
  int kk = (int)(r2 % 3), i = (int)(r2 / 3);
  dst[idx] = (bf16)src[(long)i * N * Kd * 3 + ((long)n * Kd + c) * 3 + kk];
}

__global__ __launch_bounds__(256) void cvt_bias_all(const float* __restrict__ bq,
                                                    const float* __restrict__ bk,
                                                    const float* __restrict__ bv,
                                                    float* __restrict__ dst) {
  int idx = blockIdx.x * 256 + threadIdx.x;      // L*1536
  if (idx >= L * 1536) return;
  int j = idx % 1536, i = idx / 1536;
  float v = (j < 512) ? bq[i * 512 + j] : (j < 1024) ? bk[i * 512 + j - 512]
                                                     : bv[i * 512 + j - 1024];
  dst[idx] = v;
}

// ---------------------------------------------------------------------------
extern "C" void kernel_launch(void* const* d_in, const int* in_sizes, int n_in,
                              void* d_out, int out_size, void* d_ws, size_t ws_size,
                              hipStream_t stream)
{
  const float* xin = (const float*)d_in[0];
  const float* msk = (const float*)d_in[1];
  const float* Wq  = (const float*)d_in[2];
  const float* bq  = (const float*)d_in[3];
  const float* Wk  = (const float*)d_in[4];
  const float* bk  = (const float*)d_in[5];
  const float* Wv  = (const float*)d_in[6];
  const float* bv  = (const float*)d_in[7];
  const float* Wo  = (const float*)d_in[8];
  const float* bo  = (const float*)d_in[9];
  const float* g1  = (const float*)d_in[10];
  const float* be1 = (const float*)d_in[11];
  const float* W1  = (const float*)d_in[12];
  const float* c1  = (const float*)d_in[13];
  const float* W2  = (const float*)d_in[14];
  const float* c2  = (const float*)d_in[15];
  const float* g2  = (const float*)d_in[16];
  const float* be2 = (const float*)d_in[17];

  size_t off = 0;
  char* base = (char*)d_ws;
  auto alloc = [&](size_t bytes) -> char* {
    char* r = base + off;
    off = (off + bytes + 1023) & ~(size_t)1023;
    return r;
  };
  float* x     = (float*)alloc((size_t)B * T * C * 4);
  float* ropeC = (float*)alloc((size_t)T * 16 * 4);
  float* ropeS = (float*)alloc((size_t)T * 16 * 4);
  bf16* xm  = (bf16*)alloc((size_t)B * TP * C * 2);
  bf16* hb  = (bf16*)alloc((size_t)B * TP * F * 2);
  bf16* q   = (bf16*)alloc((size_t)B * T * C * 2);
  bf16* k   = (bf16*)alloc((size_t)B * T * C * 2);
  bf16* vT  = (bf16*)alloc((size_t)B * T * C * 2);
  bf16* o   = (bf16*)alloc((size_t)B * T * C * 2);
  bf16* yb  = (bf16*)alloc((size_t)B * T * C * 2);
  // all-layer bf16 weights (one-time conversion)
  bf16* wqkv_all = (bf16*)alloc((size_t)L * 3 * C * C * 2);
  bf16* wo_all   = (bf16*)alloc((size_t)L * C * C * 2);
  bf16* w1_all   = (bf16*)alloc((size_t)L * 3 * F * C * 2);
  bf16* w2_all   = (bf16*)alloc((size_t)L * 3 * C * F * 2);
  float* bqkv_all = (float*)alloc((size_t)L * 1536 * 4);
  (void)in_sizes; (void)n_in; (void)out_size; (void)ws_size;

  // ---- one-time prologue ----
  {
    long tot = (long)B * 18 * (C + F);
    zero_pads_kernel<<<(int)((tot + 255) / 256), 256, 0, stream>>>(xm, hb);
  }
  transpose_in_kernel<<<dim3(T / 32, C / 32, B), dim3(32, 8), 0, stream>>>(xin, msk, x, xm);
  rope_tab_kernel<<<(T * 16 + 255) / 256, 256, 0, stream>>>(ropeC, ropeS);
  cvt_qkv_all<<<(int)(((long)L * 3 * C * C / 4 + 255) / 256), 256, 0, stream>>>(Wq, Wk, Wv, wqkv_all);
  cvt_wo_all<<<(int)(((long)L * C * C / 4 + 255) / 256), 256, 0, stream>>>(Wo, wo_all);
  cvt_w3_all<<<(int)(((long)L * 3 * F * C + 255) / 256), 256, 0, stream>>>(W1, w1_all, F, C);
  cvt_w3_all<<<(int)(((long)L * 3 * C * F + 255) / 256), 256, 0, stream>>>(W2, w2_all, C, F);
  cvt_bias_all<<<(L * 1536 + 255) / 256, 256, 0, stream>>>(bq, bk, bv, bqkv_all);

  for (int i = 0; i < L; ++i) {
    const bf16* wqkv = wqkv_all + (long)i * 3 * C * C;
    const bf16* wo   = wo_all + (long)i * C * C;
    const bf16* w1b  = w1_all + (long)i * 3 * F * C;
    const bf16* w2b  = w2_all + (long)i * 3 * C * F;
    const float* bqkv = bqkv_all + (long)i * 1536;

    // fused QKV projection (N=1536), v stored transposed
    gemm_kernel<64, 128, 1, 2, false, false, 1, false, false, 4>
        <<<dim3(16, 12, B), 256, 0, stream>>>(
        xm + C, wqkv, bqkv, msk, q, k, vT,
        C, C, C, C, 0,
        (long)TP * C, 0, 0, 0, (long)T * C, 0, 0);

    rope_kernel<<<(B * T * H * 16) / 256, 256, 0, stream>>>(q, k, ropeC, ropeS);

    flash_kernel<<<dim3(T / 64, B * H), 256, 0, stream>>>(q, k, vT, msk, o);

    // O projection (batch flattened: M = B*T)
    gemm_kernel<64, 64, 1, 0, false, false, 1, false, false, 4>
        <<<dim3(64, 8, 1), 256, 0, stream>>>(
        o, wo, bo + (size_t)i * C, msk, yb, nullptr, nullptr,
        C, C, C, C, 0,
        0, 0, 0, 0, 0, 0, 0);

    ln_kernel<<<B * T / 4, 256, 0, stream>>>(x, yb, g1 + (size_t)i * C, be1 + (size_t)i * C,
                                             msk, 1, 0, x, xm);

    // FFN conv1 (K=3, relu, masked output)
    gemm_kernel<128, 64, 3, 0, true, true, 1, false, false, 3>
        <<<dim3(8, 32, B), 256, 0, stream>>>(
        xm, w1b, c1 + (size_t)i * F, msk, hb + F, nullptr, nullptr,
        C, C, F, C, (long)F * C,
        (long)TP * C, 0, 0, 0, (long)TP * F, 0, 0);

    // FFN conv2 (K=3)
    gemm_kernel<64, 64, 3, 0, false, false, 1, false, false, 4>
        <<<dim3(16, 8, B), 256, 0, stream>>>(
        hb, w2b, c2 + (size_t)i * C, msk, yb, nullptr, nullptr,
        F, F, C, F, (long)C * F,
        (long)TP * F, 0, 0, 0, (long)T * C, 0, 0);

    ln_kernel<<<B * T / 4, 256, 0, stream>>>(x, yb, g2 + (size_t)i * C, be2 + (size_t)i * C,
                                             msk, 0, 1, x, xm);
  }

  transpose_out_kernel<<<dim3(T / 32, C / 32, B), dim3(32, 8), 0, stream>>>(x, msk, (float*)d_out);
}

// Round 5
// 904.844 us; speedup vs baseline: 14.5905x; 1.1189x over previous
//
#include <hip/hip_runtime.h>

typedef __bf16 bf16;
typedef __bf16 bf16x2 __attribute__((ext_vector_type(2)));
typedef __bf16 bf16x8 __attribute__((ext_vector_type(8)));
typedef __bf16 bf16x4v __attribute__((ext_vector_type(4)));
typedef float f32x4 __attribute__((ext_vector_type(4)));

constexpr int B = 4, C = 512, T = 1024, H = 8, F = 2048, L = 6;
constexpr int TP = T + 18;               // padded rows: row0 = zero, rows T+1..T+17 zero
constexpr float SCALE = 0.125f, EPS = 1e-4f;

// ---------------------------------------------------------------------------
// global -> LDS staging, 64B rows (GEMM tiles: 32 bf16 k-slice per row)
// LDS linear; swizzle applied on the per-lane GLOBAL source (involution),
// matched by the same XOR on the ds_read side.
// ---------------------------------------------------------------------------
__device__ __forceinline__ void stage_rows(const char* g, long strideB, char* lds,
                                           int nChunks, int tid) {
  const int wave = tid >> 6, lane = tid & 63;
  for (int c = wave; c < nChunks; c += 4) {
    int row = (c << 4) + (lane >> 2);
    int kq = (lane & 3) ^ ((row >> 1) & 3);
    const char* src = g + (long)row * strideB + kq * 16;
    char* dst = lds + ((long)c << 10);
    __builtin_amdgcn_global_load_lds((const __attribute__((address_space(1))) void*)src,
                                     (__attribute__((address_space(3))) void*)dst,
                                     16, 0, 0);
  }
}

// 128B rows (flash tiles: 64 bf16 per row). LDS[row][slot16] = G[row][slot ^ (row&7)].
__device__ __forceinline__ void stage_rows128(const char* g, long strideB, char* lds,
                                              int nChunks, int tid) {
  const int wave = tid >> 6, lane = tid & 63;
  for (int c = wave; c < nChunks; c += 4) {
    int row = (c << 3) + (lane >> 3);
    int kq = (lane & 7) ^ ((lane >> 3) & 7);
    const char* src = g + (long)row * strideB + kq * 16;
    char* dst = lds + ((long)c << 10);
    __builtin_amdgcn_global_load_lds((const __attribute__((address_space(1))) void*)src,
                                     (__attribute__((address_space(3))) void*)dst,
                                     16, 0, 0);
  }
}

// ---------------------------------------------------------------------------
// NT GEMM, 2-phase prefetch double-buffered LDS.
// D[m][n] = sum_k A[m][k] * Bw[n][k]  (+ kw-shifted A rows for KW=3)
// EPI: 0 = bf16 [m][ldo] (+bias, relu, maskM opts)
//      2 = QKV split with fused RoPE: n<512 -> O(q), <1024 -> O2(k),
//          else O3 = vT[n-1024][m]
// ---------------------------------------------------------------------------
template <int BM, int BN, int KW, int EPI, bool RELU, bool MASKM, int ZD,
          bool AZL, bool OZL, int MINW>
__global__ __launch_bounds__(256, MINW) void gemm_kernel(
    const bf16* __restrict__ A, const bf16* __restrict__ Bw,
    const float* __restrict__ bias, const float* __restrict__ mask,
    bf16* __restrict__ O, bf16* __restrict__ O2, bf16* __restrict__ O3,
    int lda, int ldb, int ldo, int K, long bSlice,
    long aZ1, long aZ2, long bZ1, long bZ2, long oZ1, long oZ2, int zoff,
    const float* __restrict__ ropeC, const float* __restrict__ ropeS)
{
  constexpr int WTM = BM / 2, WTN = BN / 2, FM = WTM / 16, FN = WTN / 16;
  constexpr int RA = (KW == 3) ? BM + 16 : BM;
  constexpr int ACH = RA / 16;
  constexpr int BCHS = BN / 16;
  constexpr int TCH = ACH + KW * BCHS;
  __shared__ __align__(1024) bf16 sBuf[2][TCH * 512];

  const int tid = threadIdx.x;
  const int zl = blockIdx.z, zg = zl + zoff;
  const int zb = zg / ZD, zh = zg % ZD;
  const long aOff = AZL ? (long)zl * aZ1 : (long)zb * aZ1 + (long)zh * aZ2;
  const long bOff = (long)zb * bZ1 + (long)zh * bZ2;
  const long oOff = OZL ? (long)zl * oZ1 : (long)zb * oZ1 + (long)zh * oZ2;
  const int m0 = blockIdx.x * BM, n0 = blockIdx.y * BN;
  const bf16* Ab = A + aOff + (long)m0 * lda;
  const bf16* Bb = Bw + bOff + (long)n0 * ldb;

  const int wid = tid >> 6, lane = tid & 63;
  const int wm = wid >> 1, wn = wid & 1;
  const int l16 = lane & 15, q4 = lane >> 4;

  f32x4 acc[FM][FN] = {};

  auto STAGE = [&](int k0, int buf) {
    char* sa = (char*)sBuf[buf];
    stage_rows((const char*)(Ab + k0), (long)lda * 2, sa, ACH, tid);
    #pragma unroll
    for (int kw = 0; kw < KW; ++kw)
      stage_rows((const char*)(Bb + (long)kw * bSlice + k0), (long)ldb * 2,
                 sa + (ACH + kw * BCHS) * 1024, BCHS, tid);
  };

  auto COMPUTE = [&](int buf) {
    const char* sa = (const char*)sBuf[buf];
    const char* sb = sa + ACH * 1024;
    #pragma unroll
    for (int kw = 0; kw < KW; ++kw) {
      bf16x8 af[FM], bfr[FN];
      #pragma unroll
      for (int fm = 0; fm < FM; ++fm) {
        int row = wm * WTM + fm * 16 + l16 + (KW == 3 ? kw : 0);
        unsigned ad = (unsigned)(row * 64 + q4 * 16);
        ad ^= ((ad >> 7) & 3u) << 4;
        af[fm] = *(const bf16x8*)(sa + ad);
      }
      #pragma unroll
      for (int fn = 0; fn < FN; ++fn) {
        int rn = wn * WTN + fn * 16 + l16;
        unsigned bd = (unsigned)(rn * 64 + q4 * 16);
        bd ^= ((bd >> 7) & 3u) << 4;
        bfr[fn] = *(const bf16x8*)(sb + kw * BCHS * 1024 + bd);
      }
      #pragma unroll
      for (int fm = 0; fm < FM; ++fm)
        #pragma unroll
        for (int fn = 0; fn < FN; ++fn)
          acc[fm][fn] = __builtin_amdgcn_mfma_f32_16x16x32_bf16(af[fm], bfr[fn],
                                                                acc[fm][fn], 0, 0, 0);
    }
  };

  STAGE(0, 0);
  __syncthreads();
  int cur = 0;
  for (int k0 = 32; k0 < K; k0 += 32) {
    STAGE(k0, cur ^ 1);
    COMPUTE(cur);
    __syncthreads();
    cur ^= 1;
  }
  COMPUTE(cur);

  // ---- epilogue: C/D layout col=lane&15, row=(lane>>4)*4+i ----
  float varr[FN][FM][4];
  #pragma unroll
  for (int fn = 0; fn < FN; ++fn) {
    const int nl = n0 + wn * WTN + fn * 16 + l16;
    const float bv = (bias == nullptr) ? 0.f : bias[nl];
    #pragma unroll
    for (int fm = 0; fm < FM; ++fm) {
      const int mb = m0 + wm * WTM + fm * 16 + q4 * 4;
      #pragma unroll
      for (int i = 0; i < 4; ++i) {
        float t = acc[fm][fn][i] + bv;
        if (RELU) t = fmaxf(t, 0.f);
        if (MASKM) t *= mask[(long)zb * T + mb + i];
        varr[fn][fm][i] = t;
      }
    }
  }

  if constexpr (EPI == 2) {
    // fused RoPE: head = 64 channels aligned to WTN blocks; pairs (fn0, fn1)
    // rotate channels 0..31 of each head for q (nl<512) and k (512..1023).
    if (n0 + wn * WTN < 1024) {
      #pragma unroll
      for (int fm = 0; fm < FM; ++fm) {
        const int mb = m0 + wm * WTM + fm * 16 + q4 * 4;
        #pragma unroll
        for (int i = 0; i < 4; ++i) {
          const int t = mb + i;
          float cv = ropeC[t * 16 + l16], sv = ropeS[t * 16 + l16];
          float a = varr[0][fm][i], b2 = varr[1][fm][i];
          varr[0][fm][i] = a * cv - b2 * sv;
          varr[1][fm][i] = b2 * cv + a * sv;
        }
      }
    }
  }

  #pragma unroll
  for (int fn = 0; fn < FN; ++fn) {
    const int nl = n0 + wn * WTN + fn * 16 + l16;
    #pragma unroll
    for (int fm = 0; fm < FM; ++fm) {
      const int mb = m0 + wm * WTM + fm * 16 + q4 * 4;
      if constexpr (EPI == 2) {
        if (nl < 1024) {
          bf16* dst = (nl < 512 ? O : O2) + oOff + (nl & 511);
          #pragma unroll
          for (int i = 0; i < 4; ++i)
            dst[(long)(mb + i) * C] = (bf16)varr[fn][fm][i];
        } else {
          bf16x4v tv;
          #pragma unroll
          for (int i = 0; i < 4; ++i) tv[i] = (bf16)varr[fn][fm][i];
          *(bf16x4v*)(O3 + oOff + (long)(nl - 1024) * T + mb) = tv;
        }
      } else {
        bf16* dst = O + oOff;
        #pragma unroll
        for (int i = 0; i < 4; ++i)
          dst[(long)(mb + i) * ldo + nl] = (bf16)varr[fn][fm][i];
      }
    }
  }
}

// ---------------------------------------------------------------------------
// Flash attention: one block = 64 q-rows x one (b,h). 4 waves x 16 q-rows.
// ---------------------------------------------------------------------------
__global__ __launch_bounds__(256, 3) void flash_kernel(
    const bf16* __restrict__ q, const bf16* __restrict__ k,
    const bf16* __restrict__ vT, const float* __restrict__ mask,
    bf16* __restrict__ o)
{
  __shared__ __align__(1024) char sQ[64 * 128];
  __shared__ __align__(1024) char sK[2][64 * 128];
  __shared__ __align__(1024) char sV[2][64 * 128];
  __shared__ __align__(1024) char sP[4][16 * 128];

  const int tid = threadIdx.x;
  const int w = tid >> 6, lane = tid & 63;
  const int l16 = lane & 15, q4 = lane >> 4;
  const int q0 = blockIdx.x * 64;
  const int bh = blockIdx.y;
  const int b = bh >> 3, h = bh & 7;

  const bf16* qb = q + ((long)b * T + q0) * C + h * 64;
  const bf16* kb = k + (long)b * T * C + h * 64;
  const bf16* vb = vT + (long)b * C * T + (long)h * 64 * T;

  stage_rows128((const char*)qb, (long)C * 2, sQ, 8, tid);
  stage_rows128((const char*)kb, (long)C * 2, sK[0], 8, tid);
  stage_rows128((const char*)vb, (long)T * 2, sV[0], 8, tid);
  __syncthreads();

  bf16x8 af_q[2];
  {
    const int r = w * 16 + l16;
    #pragma unroll
    for (int kk = 0; kk < 2; ++kk) {
      unsigned off = (unsigned)(kk * 64 + q4 * 16) ^ ((unsigned)(r & 7) << 4);
      af_q[kk] = *(const bf16x8*)(sQ + r * 128 + off);
    }
  }

  float mq[4];
  #pragma unroll
  for (int i = 0; i < 4; ++i)
    mq[i] = mask[(long)b * T + q0 + w * 16 + q4 * 4 + i];

  f32x4 accO[4] = {};
  float mrun[4] = {-1e30f, -1e30f, -1e30f, -1e30f};
  float lrun[4] = {0.f, 0.f, 0.f, 0.f};
  char* sPw = sP[w];

  int cur = 0;
  for (int it = 0; it < 16; ++it) {
    if (it < 15) {
      stage_rows128((const char*)(kb + (long)(it + 1) * 64 * C), (long)C * 2, sK[cur ^ 1], 8, tid);
      stage_rows128((const char*)(vb + (it + 1) * 64), (long)T * 2, sV[cur ^ 1], 8, tid);
    }
    f32x4 s[4] = {};
    #pragma unroll
    for (int kk = 0; kk < 2; ++kk) {
      #pragma unroll
      for (int fn = 0; fn < 4; ++fn) {
        const int rn = fn * 16 + l16;
        unsigned off = (unsigned)(kk * 64 + q4 * 16) ^ ((unsigned)(rn & 7) << 4);
        bf16x8 kf = *(const bf16x8*)(sK[cur] + rn * 128 + off);
        s[fn] = __builtin_amdgcn_mfma_f32_16x16x32_bf16(af_q[kk], kf, s[fn], 0, 0, 0);
      }
    }
    float mk[4];
    #pragma unroll
    for (int fn = 0; fn < 4; ++fn)
      mk[fn] = mask[(long)b * T + it * 64 + fn * 16 + l16];
    float sv[4][4];
    #pragma unroll
    for (int fn = 0; fn < 4; ++fn)
      #pragma unroll
      for (int i = 0; i < 4; ++i) {
        float xval = s[fn][i] * SCALE;
        sv[fn][i] = (mq[i] * mk[fn] > 0.f) ? xval : -10000.f;
      }
    float cor[4];
    #pragma unroll
    for (int i = 0; i < 4; ++i) {
      float m0 = fmaxf(fmaxf(sv[0][i], sv[1][i]), fmaxf(sv[2][i], sv[3][i]));
      #pragma unroll
      for (int st = 1; st < 16; st <<= 1) m0 = fmaxf(m0, __shfl_xor(m0, st, 64));
      float mnew = fmaxf(mrun[i], m0);
      cor[i] = __expf(mrun[i] - mnew);
      mrun[i] = mnew;
    }
    float rs[4] = {0.f, 0.f, 0.f, 0.f};
    #pragma unroll
    for (int fn = 0; fn < 4; ++fn)
      #pragma unroll
      for (int i = 0; i < 4; ++i) {
        float p = __expf(sv[fn][i] - mrun[i]);
        rs[i] += p;
        const int row = q4 * 4 + i;
        unsigned off = (unsigned)((fn * 16 + l16) * 2) ^ ((unsigned)(row & 7) << 4);
        *(bf16*)(sPw + row * 128 + off) = (bf16)p;
      }
    #pragma unroll
    for (int i = 0; i < 4; ++i) {
      #pragma unroll
      for (int st = 1; st < 16; st <<= 1) rs[i] += __shfl_xor(rs[i], st, 64);
      lrun[i] = lrun[i] * cor[i] + rs[i];
    }
    #pragma unroll
    for (int fn = 0; fn < 4; ++fn)
      #pragma unroll
      for (int i = 0; i < 4; ++i) accO[fn][i] *= cor[i];
    #pragma unroll
    for (int kk = 0; kk < 2; ++kk) {
      unsigned poff = (unsigned)(kk * 64 + q4 * 16) ^ ((unsigned)(l16 & 7) << 4);
      bf16x8 pf = *(const bf16x8*)(sPw + l16 * 128 + poff);
      #pragma unroll
      for (int fn = 0; fn < 4; ++fn) {
        const int rn = fn * 16 + l16;
        unsigned off = (unsigned)(kk * 64 + q4 * 16) ^ ((unsigned)(rn & 7) << 4);
        bf16x8 vf = *(const bf16x8*)(sV[cur] + rn * 128 + off);
        accO[fn] = __builtin_amdgcn_mfma_f32_16x16x32_bf16(pf, vf, accO[fn], 0, 0, 0);
      }
    }
    __syncthreads();
    cur ^= 1;
  }

  float linv[4];
  #pragma unroll
  for (int i = 0; i < 4; ++i) linv[i] = 1.f / lrun[i];
  #pragma unroll
  for (int fn = 0; fn < 4; ++fn)
    #pragma unroll
    for (int i = 0; i < 4; ++i)
      o[((long)b * T + q0 + w * 16 + q4 * 4 + i) * C + h * 64 + fn * 16 + l16] =
          (bf16)(accO[fn][i] * linv[i]);
}

// ---------------- RoPE table ----------------
__global__ __launch_bounds__(256) void rope_tab_kernel(float* __restrict__ cosT,
                                                       float* __restrict__ sinT) {
  int idx = blockIdx.x * 256 + threadIdx.x;
  if (idx >= T * 16) return;
  int t = idx >> 4, j = idx & 15;
  float theta = powf(10000.f, -(float)j / 16.f);
  float s, c;
  sincosf((float)t * theta, &s, &c);
  cosT[idx] = c;
  sinT[idx] = s;
}

// ---------------- fused residual + LayerNorm over contiguous C ----------------
__global__ __launch_bounds__(256) void ln_kernel(
    const float* __restrict__ x, const bf16* __restrict__ y,
    const float* __restrict__ gamma, const float* __restrict__ beta,
    const float* __restrict__ mask, int maskA, int maskY,
    float* __restrict__ xout, bf16* __restrict__ xm)
{
  const int w = threadIdx.x >> 6, lane = threadIdx.x & 63;
  const long row = (long)blockIdx.x * 4 + w;
  const int b = (int)(row >> 10), t = (int)(row & 1023);
  const float* xr = x + row * C;
  const bf16* yr = y + row * C;
  const float m = mask[(long)b * T + t];
  const float fa = maskA ? m : 1.f, fy = maskY ? m : 1.f;
  float4 x0 = *(const float4*)(xr + lane * 8);
  float4 x1 = *(const float4*)(xr + lane * 8 + 4);
  bf16x8 yv = *(const bf16x8*)(yr + lane * 8);
  float vals[8] = {x0.x, x0.y, x0.z, x0.w, x1.x, x1.y, x1.z, x1.w};
  float sum = 0.f, sq = 0.f;
  #pragma unroll
  for (int i = 0; i < 8; ++i) {
    vals[i] = vals[i] * fa + (float)yv[i] * fy;
    sum += vals[i]; sq += vals[i] * vals[i];
  }
  #pragma unroll
  for (int s = 1; s < 64; s <<= 1) {
    sum += __shfl_xor(sum, s, 64);
    sq  += __shfl_xor(sq, s, 64);
  }
  float mean = sum * (1.f / C);
  float rstd = rsqrtf(sq * (1.f / C) - mean * mean + EPS);
  float4 g0 = *(const float4*)(gamma + lane * 8), g1v = *(const float4*)(gamma + lane * 8 + 4);
  float4 b0 = *(const float4*)(beta + lane * 8),  b1v = *(const float4*)(beta + lane * 8 + 4);
  float gg[8] = {g0.x, g0.y, g0.z, g0.w, g1v.x, g1v.y, g1v.z, g1v.w};
  float bb[8] = {b0.x, b0.y, b0.z, b0.w, b1v.x, b1v.y, b1v.z, b1v.w};
  float o[8]; bf16x8 xmv;
  #pragma unroll
  for (int i = 0; i < 8; ++i) {
    o[i] = (vals[i] - mean) * rstd * gg[i] + bb[i];
    xmv[i] = (bf16)(o[i] * m);
  }
  *(float4*)(xout + row * C + lane * 8)     = make_float4(o[0], o[1], o[2], o[3]);
  *(float4*)(xout + row * C + lane * 8 + 4) = make_float4(o[4], o[5], o[6], o[7]);
  *(bf16x8*)(xm + ((long)b * TP + t + 1) * C + lane * 8) = xmv;
}

// ---------------- transposes [b][C][T] <-> [b][t][C] ----------------
__global__ __launch_bounds__(256) void transpose_in_kernel(const float* __restrict__ xin,
                                                           const float* __restrict__ mask,
                                                           float* __restrict__ x,
                                                           bf16* __restrict__ xm) {
  __shared__ float tile[32][33];
  int tx = threadIdx.x, ty = threadIdx.y;
  int t0 = blockIdx.x * 32, c0 = blockIdx.y * 32, b = blockIdx.z;
  #pragma unroll
  for (int i = 0; i < 4; ++i)
    tile[ty + i * 8][tx] = xin[((long)b * C + c0 + ty + i * 8) * T + t0 + tx];
  __syncthreads();
  #pragma unroll
  for (int i = 0; i < 4; ++i) {
    int t = t0 + ty + i * 8;
    float val = tile[tx][ty + i * 8];
    float m = mask[(long)b * T + t];
    x[((long)b * T + t) * C + c0 + tx] = val;
    xm[((long)b * TP + t + 1) * C + c0 + tx] = (bf16)(val * m);
  }
}

__global__ __launch_bounds__(256) void transpose_out_kernel(const float* __restrict__ x,
                                                            const float* __restrict__ mask,
                                                            float* __restrict__ out) {
  __shared__ float tile[32][33];
  int tx = threadIdx.x, ty = threadIdx.y;
  int t0 = blockIdx.x * 32, c0 = blockIdx.y * 32, b = blockIdx.z;
  #pragma unroll
  for (int i = 0; i < 4; ++i)
    tile[ty + i * 8][tx] = x[((long)b * T + t0 + ty + i * 8) * C + c0 + tx];
  __syncthreads();
  #pragma unroll
  for (int i = 0; i < 4; ++i) {
    int t = t0 + tx;
    out[((long)b * C + c0 + ty + i * 8) * T + t] = tile[tx][ty + i * 8] * mask[(long)b * T + t];
  }
}

// ---------------- zero halo rows of padded activation buffers ----------------
__global__ __launch_bounds__(256) void zero_pads_kernel(bf16* __restrict__ xm, bf16* __restrict__ h) {
  long idx = (long)blockIdx.x * 256 + threadIdx.x;
  const long n1 = (long)B * 18 * C;
  const long n2 = (long)B * 18 * F;
  if (idx < n1) {
    int c = (int)(idx % C); int r = (int)((idx / C) % 18); int b = (int)(idx / (18L * C));
    int p = (r == 0) ? 0 : (T + r);
    xm[((long)b * TP + p) * C + c] = (bf16)0.f;
  } else if (idx < n1 + n2) {
    long j = idx - n1;
    int c = (int)(j % F); int r = (int)((j / F) % 18); int b = (int)(j / (18L * F));
    int p = (r == 0) ? 0 : (T + r);
    h[((long)b * TP + p) * F + c] = (bf16)0.f;
  }
}

// ---------------- one-time all-layer weight conversions ----------------
__global__ __launch_bounds__(256) void cvt_qkv_all(const float* __restrict__ Wq,
                                                   const float* __restrict__ Wk,
                                                   const float* __restrict__ Wv,
                                                   bf16* __restrict__ dst) {
  long idx = (long)blockIdx.x * 256 + threadIdx.x;   // L*3*C*C/4
  if (idx >= (long)L * 3 * C * C / 4) return;
  int c4 = (int)(idx & 127) * 4;
  int n = (int)((idx >> 7) & 511);
  int s2 = (int)(idx >> 16);
  int slot = s2 % 3, i = s2 / 3;
  const float* src = (slot == 0 ? Wq : slot == 1 ? Wk : Wv) + (long)i * C * C + (long)n * C + c4;
  float4 v = *(const float4*)src;
  bf16x4v d = {(bf16)v.x, (bf16)v.y, (bf16)v.z, (bf16)v.w};
  *(bf16x4v*)(dst + (((long)(i * 3 + slot) * 512 + n) * 512 + c4)) = d;
}

__global__ __launch_bounds__(256) void cvt_wo_all(const float* __restrict__ src,
                                                  bf16* __restrict__ dst) {
  long idx = (long)blockIdx.x * 256 + threadIdx.x;   // L*C*C/4
  if (idx >= (long)L * C * C / 4) return;
  float4 v = *(const float4*)(src + idx * 4);
  bf16x4v d = {(bf16)v.x, (bf16)v.y, (bf16)v.z, (bf16)v.w};
  *(bf16x4v*)(dst + idx * 4) = d;
}

// w1/w2: dst[i][k][n][c] = src[i][(n*Kd + c)*3 + k] — coalesced 2-wide:
// each thread reads 6 contiguous floats (2 c-triples), writes bf16x2 to 3 planes.
__global__ __launch_bounds__(256) void cvt_w3_all(const float* __restrict__ src,
                                                  bf16* __restrict__ dst, int N, int Kd) {
  long idx = (long)blockIdx.x * 256 + threadIdx.x;   // L*N*Kd/2
  long total = (long)L * N * Kd / 2;
  if (idx >= total) return;
  const int half = Kd >> 1;
  int c2 = (int)(idx % half) * 2;
  long r = idx / half;
  int n = (int)(r % N);
  int i = (int)(r / N);
  const float* s = src + ((long)i * N * Kd + (long)n * Kd + c2) * 3;
  float v0 = s[0], v1 = s[1], v2 = s[2], v3 = s[3], v4 = s[4], v5 = s[5];
  long plane = (long)N * Kd;
  long baseo = (long)i * 3 * plane + (long)n * Kd + c2;
  bf16x2 d0 = {(bf16)v0, (bf16)v3};
  bf16x2 d1 = {(bf16)v1, (bf16)v4};
  bf16x2 d2 = {(bf16)v2, (bf16)v5};
  *(bf16x2*)(dst + baseo)             = d0;
  *(bf16x2*)(dst + baseo + plane)     = d1;
  *(bf16x2*)(dst + baseo + 2 * plane) = d2;
}

__global__ __launch_bounds__(256) void cvt_bias_all(const float* __restrict__ bq,
                                                    const float* __restrict__ bk,
                                                    const float* __restrict__ bv,
                                                    float* __restrict__ dst) {
  int idx = blockIdx.x * 256 + threadIdx.x;      // L*1536
  if (idx >= L * 1536) return;
  int j = idx % 1536, i = idx / 1536;
  float v = (j < 512) ? bq[i * 512 + j] : (j < 1024) ? bk[i * 512 + j - 512]
                                                     : bv[i * 512 + j - 1024];
  dst[idx] = v;
}

// ---------------------------------------------------------------------------
extern "C" void kernel_launch(void* const* d_in, const int* in_sizes, int n_in,
                              void* d_out, int out_size, void* d_ws, size_t ws_size,
                              hipStream_t stream)
{
  const float* xin = (const float*)d_in[0];
  const float* msk = (const float*)d_in[1];
  const float* Wq  = (const float*)d_in[2];
  const float* bq  = (const float*)d_in[3];
  const float* Wk  = (const float*)d_in[4];
  const float* bk  = (const float*)d_in[5];
  const float* Wv  = (const float*)d_in[6];
  const float* bv  = (const float*)d_in[7];
  const float* Wo  = (const float*)d_in[8];
  const float* bo  = (const float*)d_in[9];
  const float* g1  = (const float*)d_in[10];
  const float* be1 = (const float*)d_in[11];
  const float* W1  = (const float*)d_in[12];
  const float* c1  = (const float*)d_in[13];
  const float* W2  = (const float*)d_in[14];
  const float* c2  = (const float*)d_in[15];
  const float* g2  = (const float*)d_in[16];
  const float* be2 = (const float*)d_in[17];

  size_t off = 0;
  char* base = (char*)d_ws;
  auto alloc = [&](size_t bytes) -> char* {
    char* r = base + off;
    off = (off + bytes + 1023) & ~(size_t)1023;
    return r;
  };
  float* x     = (float*)alloc((size_t)B * T * C * 4);
  float* ropeC = (float*)alloc((size_t)T * 16 * 4);
  float* ropeS = (float*)alloc((size_t)T * 16 * 4);
  bf16* xm  = (bf16*)alloc((size_t)B * TP * C * 2);
  bf16* hb  = (bf16*)alloc((size_t)B * TP * F * 2);
  bf16* q   = (bf16*)alloc((size_t)B * T * C * 2);
  bf16* k   = (bf16*)alloc((size_t)B * T * C * 2);
  bf16* vT  = (bf16*)alloc((size_t)B * T * C * 2);
  bf16* o   = (bf16*)alloc((size_t)B * T * C * 2);
  bf16* yb  = (bf16*)alloc((size_t)B * T * C * 2);
  bf16* wqkv_all = (bf16*)alloc((size_t)L * 3 * C * C * 2);
  bf16* wo_all   = (bf16*)alloc((size_t)L * C * C * 2);
  bf16* w1_all   = (bf16*)alloc((size_t)L * 3 * F * C * 2);
  bf16* w2_all   = (bf16*)alloc((size_t)L * 3 * C * F * 2);
  float* bqkv_all = (float*)alloc((size_t)L * 1536 * 4);
  (void)in_sizes; (void)n_in; (void)out_size; (void)ws_size;

  // ---- one-time prologue ----
  {
    long tot = (long)B * 18 * (C + F);
    zero_pads_kernel<<<(int)((tot + 255) / 256), 256, 0, stream>>>(xm, hb);
  }
  transpose_in_kernel<<<dim3(T / 32, C / 32, B), dim3(32, 8), 0, stream>>>(xin, msk, x, xm);
  rope_tab_kernel<<<(T * 16 + 255) / 256, 256, 0, stream>>>(ropeC, ropeS);
  cvt_qkv_all<<<(int)(((long)L * 3 * C * C / 4 + 255) / 256), 256, 0, stream>>>(Wq, Wk, Wv, wqkv_all);
  cvt_wo_all<<<(int)(((long)L * C * C / 4 + 255) / 256), 256, 0, stream>>>(Wo, wo_all);
  cvt_w3_all<<<(int)(((long)L * F * C / 2 + 255) / 256), 256, 0, stream>>>(W1, w1_all, F, C);
  cvt_w3_all<<<(int)(((long)L * C * F / 2 + 255) / 256), 256, 0, stream>>>(W2, w2_all, C, F);
  cvt_bias_all<<<(L * 1536 + 255) / 256, 256, 0, stream>>>(bq, bk, bv, bqkv_all);

  for (int i = 0; i < L; ++i) {
    const bf16* wqkv = wqkv_all + (long)i * 3 * C * C;
    const bf16* wo   = wo_all + (long)i * C * C;
    const bf16* w1b  = w1_all + (long)i * 3 * F * C;
    const bf16* w2b  = w2_all + (long)i * 3 * C * F;
    const float* bqkv = bqkv_all + (long)i * 1536;

    // fused QKV projection (N=1536) + RoPE in epilogue; v stored transposed
    gemm_kernel<64, 128, 1, 2, false, false, 1, false, false, 4>
        <<<dim3(16, 12, B), 256, 0, stream>>>(
        xm + C, wqkv, bqkv, msk, q, k, vT,
        C, C, C, C, 0,
        (long)TP * C, 0, 0, 0, (long)T * C, 0, 0, ropeC, ropeS);

    flash_kernel<<<dim3(T / 64, B * H), 256, 0, stream>>>(q, k, vT, msk, o);

    // O projection (batch flattened: M = B*T)
    gemm_kernel<64, 64, 1, 0, false, false, 1, false, false, 4>
        <<<dim3(64, 8, 1), 256, 0, stream>>>(
        o, wo, bo + (size_t)i * C, msk, yb, nullptr, nullptr,
        C, C, C, C, 0,
        0, 0, 0, 0, 0, 0, 0, nullptr, nullptr);

    ln_kernel<<<B * T / 4, 256, 0, stream>>>(x, yb, g1 + (size_t)i * C, be1 + (size_t)i * C,
                                             msk, 1, 0, x, xm);

    // FFN conv1 (K=3, relu, masked output) — 128x128 tile (FM=FN=4)
    gemm_kernel<128, 128, 3, 0, true, true, 1, false, false, 2>
        <<<dim3(8, 16, B), 256, 0, stream>>>(
        xm, w1b, c1 + (size_t)i * F, msk, hb + F, nullptr, nullptr,
        C, C, F, C, (long)F * C,
        (long)TP * C, 0, 0, 0, (long)TP * F, 0, 0, nullptr, nullptr);

    // FFN conv2 (K=3)
    gemm_kernel<64, 64, 3, 0, false, false, 1, false, false, 4>
        <<<dim3(16, 8, B), 256, 0, stream>>>(
        hb, w2b, c2 + (size_t)i * C, msk, yb, nullptr, nullptr,
        F, F, C, F, (long)C * F,
        (long)TP * F, 0, 0, 0, (long)T * C, 0, 0, nullptr, nullptr);

    ln_kernel<<<B * T / 4, 256, 0, stream>>>(x, yb, g2 + (size_t)i * C, be2 + (size_t)i * C,
                                             msk, 0, 1, x, xm);
  }

  transpose_out_kernel<<<dim3(T / 32, C / 32, B), dim3(32, 8), 0, stream>>>(x, msk, (float*)d_out);
}